// Round 5
// baseline (2391.172 us; speedup 1.0000x reference)
//
#include <hip/hip_runtime.h>

#define NN 50000
#define NE 800000
#define DD 128
#define NB 782          // buckets of 64 nodes: 782*64 = 50048 >= NN
#define BSTRIDE 784     // per-conv stride for bucket arrays
#define CHUNK 8192      // edges per binning block
#define BIN_BLOCKS ((NE + CHUNK - 1) / CHUNK)   // 98

__device__ __forceinline__ int clampn(int v) {
    return v < 0 ? 0 : (v >= NN ? NN - 1 : v);
}

// ---- pass 1: per-bucket edge counts (LDS-aggregated, few global atomics) ----
__global__ __launch_bounds__(256) void k_bcnt3(const int* __restrict__ e0,
                                               const int* __restrict__ e1,
                                               const int* __restrict__ e2,
                                               int* __restrict__ bHist) {
    __shared__ int hist[NB];
    const int* ei = (blockIdx.y == 0 ? e0 : blockIdx.y == 1 ? e1 : e2);
    int t = threadIdx.x;
    for (int b = t; b < NB; b += 256) hist[b] = 0;
    __syncthreads();
    int base = blockIdx.x * CHUNK;
    int chunk = NE - base; if (chunk > CHUNK) chunk = CHUNK;
    for (int i = t; i < chunk; i += 256) {
        int d = clampn(ei[NE + base + i]);
        atomicAdd(&hist[d >> 6], 1);
    }
    __syncthreads();
    for (int b = t; b < NB; b += 256)
        if (hist[b]) atomicAdd(&bHist[blockIdx.y * BSTRIDE + b], hist[b]);
}

// ---- pass 2: scan bucket counts -> bOff (exclusive) and bCur (cursors) ----
__global__ __launch_bounds__(64) void k_bscan3(const int* __restrict__ bHist,
                                               int* __restrict__ bOff,
                                               int* __restrict__ bCur) {
    int conv = blockIdx.x;
    int lane = threadIdx.x;
    const int PER = (NB + 63) / 64;   // 13
    int basei = lane * PER;
    int loc[PER];
    int s = 0;
    for (int j = 0; j < PER; ++j) {
        int b = basei + j;
        int h = (b < NB) ? bHist[conv * BSTRIDE + b] : 0;
        loc[j] = h; s += h;
    }
    int incl = s;
    for (int off = 1; off < 64; off <<= 1) {
        int u = __shfl_up(incl, off);
        if (lane >= off) incl += u;
    }
    int run = incl - s;
    for (int j = 0; j < PER; ++j) {
        int b = basei + j;
        if (b < NB) {
            bOff[conv * BSTRIDE + b] = run;
            bCur[conv * BSTRIDE + b] = run;
            run += loc[j];
        }
    }
    if (lane == 63) bOff[conv * BSTRIDE + NB] = incl;   // total (= NE)
}

// ---- pass 3: block-local counting sort by bucket, coalesced flush ----
__global__ __launch_bounds__(256) void k_bin3(const int* __restrict__ e0,
                                              const int* __restrict__ e1,
                                              const int* __restrict__ e2,
                                              int* __restrict__ bCur,
                                              unsigned int* __restrict__ binned) {
    __shared__ int hist[NB];
    __shared__ int off[NB];
    __shared__ int delta[NB];
    __shared__ unsigned int stage[CHUNK];
    __shared__ unsigned short sbuck[CHUNK];
    const int* ei = (blockIdx.y == 0 ? e0 : blockIdx.y == 1 ? e1 : e2);
    int conv = blockIdx.y;
    int t = threadIdx.x;
    int base = blockIdx.x * CHUNK;
    int chunk = NE - base; if (chunk > CHUNK) chunk = CHUNK;

    for (int b = t; b < NB; b += 256) hist[b] = 0;
    __syncthreads();
    // Pass A: local bucket histogram
    for (int i = t; i < chunk; i += 256) {
        int d = clampn(ei[NE + base + i]);
        atomicAdd(&hist[d >> 6], 1);
    }
    __syncthreads();
    // wave 0: exclusive scan hist -> off
    if (t < 64) {
        const int PER = (NB + 63) / 64;
        int basei = t * PER;
        int loc[(NB + 63) / 64];
        int s = 0;
        for (int j = 0; j < PER; ++j) {
            int b = basei + j;
            int h = (b < NB) ? hist[b] : 0;
            loc[j] = h; s += h;
        }
        int incl = s;
        for (int o = 1; o < 64; o <<= 1) {
            int u = __shfl_up(incl, o);
            if (t >= o) incl += u;
        }
        int run = incl - s;
        for (int j = 0; j < PER; ++j) {
            int b = basei + j;
            if (b < NB) { off[b] = run; run += loc[j]; }
        }
    }
    __syncthreads();
    // reserve global ranges (one atomic per non-empty bucket)
    for (int b = t; b < NB; b += 256) {
        if (hist[b]) {
            int gp = atomicAdd(&bCur[conv * BSTRIDE + b], hist[b]);
            delta[b] = gp - off[b];
        }
    }
    __syncthreads();
    // Pass B: stage entries grouped by bucket
    for (int i = t; i < chunk; i += 256) {
        int s = clampn(ei[base + i]);
        int d = clampn(ei[NE + base + i]);
        int b = d >> 6;
        int slot = atomicAdd(&off[b], 1);
        stage[slot] = (unsigned int)s | ((unsigned int)(d & 63) << 16);
        sbuck[slot] = (unsigned short)b;
    }
    __syncthreads();
    // flush: mostly-contiguous runs per bucket
    for (int i = t; i < chunk; i += 256)
        binned[(long)conv * NE + delta[sbuck[i]] + i] = stage[i];
}

// ---- pass 4: per-node indegree from binned (no global atomics) ----
__global__ __launch_bounds__(64) void k_ndeg3(const unsigned int* __restrict__ binned,
                                              const int* __restrict__ bOff,
                                              int* __restrict__ deg) {
    __shared__ int cnt[64];
    int b = blockIdx.x, conv = blockIdx.y;
    int t = threadIdx.x;
    cnt[t] = 0;
    __syncthreads();
    int beg = bOff[conv * BSTRIDE + b], end = bOff[conv * BSTRIDE + b + 1];
    const unsigned int* bp = binned + (long)conv * NE;
    for (int i = beg + t; i < end; i += 64)
        atomicAdd(&cnt[bp[i] >> 16], 1);
    __syncthreads();
    int v = b * 64 + t;
    if (v < NN) deg[conv * NN + v] = cnt[t];
}

// ---- h' = (x @ W) * rsqrt(deg+1), all f32. 32 rows/block, 4x4 register tile ----
__global__ __launch_bounds__(256) void k_gemmf(const float* __restrict__ x,
                                               const float* __restrict__ W,
                                               const int* __restrict__ deg,
                                               float* __restrict__ hp, int n) {
    __shared__ float wl[DD * DD];
    __shared__ float xs[32 * DD];
    int tid = threadIdx.x;
    int base = blockIdx.x * 32;

    const float4* W4 = reinterpret_cast<const float4*>(W);
    float4* wl4 = reinterpret_cast<float4*>(wl);
    for (int it = 0; it < 16; ++it) wl4[it * 256 + tid] = W4[it * 256 + tid];
    float4* xs4 = reinterpret_cast<float4*>(xs);
    const float4* x4p = reinterpret_cast<const float4*>(x);
    for (int it = 0; it < 4; ++it) {
        int idx = it * 256 + tid;
        int row = idx >> 5, col4 = idx & 31;
        int r = base + row;
        xs4[idx] = (r < n) ? x4p[(long)r * 32 + col4] : float4{0.f, 0.f, 0.f, 0.f};
    }
    __syncthreads();

    int cg = tid & 31, rg = tid >> 5;
    int c0 = cg * 4;
    float acc[4][4] = {};
    for (int kk = 0; kk < 32; ++kk) {
        float4 xv[4], wv[4];
#pragma unroll
        for (int i = 0; i < 4; ++i)
            xv[i] = *reinterpret_cast<const float4*>(&xs[(rg * 4 + i) * DD + kk * 4]);
#pragma unroll
        for (int q = 0; q < 4; ++q)
            wv[q] = *reinterpret_cast<const float4*>(&wl[(kk * 4 + q) * DD + c0]);
#pragma unroll
        for (int i = 0; i < 4; ++i) {
#pragma unroll
            for (int j = 0; j < 4; ++j) {
                acc[i][j] += xv[i].x * (&wv[0].x)[j]
                           + xv[i].y * (&wv[1].x)[j]
                           + xv[i].z * (&wv[2].x)[j]
                           + xv[i].w * (&wv[3].x)[j];
            }
        }
    }
#pragma unroll
    for (int i = 0; i < 4; ++i) {
        int r = base + rg * 4 + i;
        if (r < n) {
            float dv = rsqrtf((float)(deg[r] + 1));
            float4 o = {acc[i][0] * dv, acc[i][1] * dv, acc[i][2] * dv, acc[i][3] * dv};
            *reinterpret_cast<float4*>(&hp[(long)r * DD + c0]) = o;
        }
    }
}

// ---- fused bucket gather + self-loop + relu + pool: block per 64-node bucket ----
__global__ __launch_bounds__(256) void k_bgather(const float* __restrict__ hp,
                                                 const unsigned int* __restrict__ binned,
                                                 const int* __restrict__ bOff,
                                                 const int* __restrict__ deg,
                                                 const float* __restrict__ bias,
                                                 float* __restrict__ gout) {
    __shared__ float acc[64 * DD];     // 32 KB
    __shared__ float red[256];
    int t = threadIdx.x;
    int b = blockIdx.x;
    int lane = t & 63, wv = t >> 6;
    int half = lane >> 5, l32 = lane & 31;

    for (int i = t; i < 64 * DD; i += 256) acc[i] = 0.f;
    __syncthreads();

    int beg = bOff[b], end = bOff[b + 1];
    for (int wbase = beg + wv * 64; wbase < end; wbase += 256) {
        int cnt = end - wbase; if (cnt > 64) cnt = 64;
        unsigned int ent = (wbase + lane < end) ? binned[wbase + lane] : 0u;
        if (cnt == 64) {
#pragma unroll 8
            for (int k = 0; k < 64; k += 2) {
                unsigned int e = __shfl(ent, k + half);
                int s = (int)(e & 0xFFFFu);
                int dl = (int)(e >> 16);
                float v0 = hp[s * DD + l32];
                float v1 = hp[s * DD + 32 + l32];
                float v2 = hp[s * DD + 64 + l32];
                float v3 = hp[s * DD + 96 + l32];
                atomicAdd(&acc[dl * DD + l32], v0);
                atomicAdd(&acc[dl * DD + 32 + l32], v1);
                atomicAdd(&acc[dl * DD + 64 + l32], v2);
                atomicAdd(&acc[dl * DD + 96 + l32], v3);
            }
        } else {
            for (int k = 0; k < cnt; k += 2) {
                int idx = k + half;
                unsigned int e = __shfl(ent, idx);
                if (idx < cnt) {
                    int s = (int)(e & 0xFFFFu);
                    int dl = (int)(e >> 16);
                    float v0 = hp[s * DD + l32];
                    float v1 = hp[s * DD + 32 + l32];
                    float v2 = hp[s * DD + 64 + l32];
                    float v3 = hp[s * DD + 96 + l32];
                    atomicAdd(&acc[dl * DD + l32], v0);
                    atomicAdd(&acc[dl * DD + 32 + l32], v1);
                    atomicAdd(&acc[dl * DD + 64 + l32], v2);
                    atomicAdd(&acc[dl * DD + 96 + l32], v3);
                }
            }
        }
    }
    __syncthreads();

    // epilogue: relu(dinv*(acc + self) + bias) pooled over the bucket's nodes
    int ch = t & 127;
    float bv = bias[ch];
    float ps = 0.f;
    for (int dl = t >> 7; dl < 64; dl += 2) {
        int v = b * 64 + dl;
        if (v < NN) {
            float x = acc[dl * DD + ch] + hp[(long)v * DD + ch];
            float val = rsqrtf((float)(deg[v] + 1)) * x + bv;
            ps += fmaxf(val, 0.f);
        }
    }
    red[t] = ps;
    __syncthreads();
    if (t < DD) unsafeAtomicAdd(&gout[t], red[t] + red[t + 128]);
}

// ---- head MLP: attention over 3 pooled signatures + FiLM gates ----
__global__ __launch_bounds__(128) void k_head(const float* __restrict__ g,
    const float* __restrict__ w1, const float* __restrict__ b1,
    const float* __restrict__ w2, const float* __restrict__ b2,
    const float* __restrict__ w3, const float* __restrict__ b3,
    const float* __restrict__ f1w, const float* __restrict__ f1b,
    const float* __restrict__ f2w, const float* __restrict__ f2b,
    float* __restrict__ out) {
    __shared__ float xin[384], h1[128], h2[128], aw[3], xctx[128];
    int t = threadIdx.x;
    for (int i = t; i < 384; i += 128) xin[i] = g[i];
    __syncthreads();
    float s = b1[t];
    for (int j = 0; j < 384; ++j) s += xin[j] * w1[t * 384 + j];
    h1[t] = fmaxf(s, 0.f);
    __syncthreads();
    s = b2[t];
    for (int j = 0; j < 128; ++j) s += h1[j] * w2[t * 128 + j];
    h2[t] = fmaxf(s, 0.f);
    __syncthreads();
    if (t < 3) {
        float sl = b3[t];
        for (int j = 0; j < 128; ++j) sl += h2[j] * w3[t * 128 + j];
        aw[t] = sl;
    }
    __syncthreads();
    if (t == 0) {
        float mx = fmaxf(aw[0], fmaxf(aw[1], aw[2]));
        float e0 = expf(aw[0] - mx), e1 = expf(aw[1] - mx), e2 = expf(aw[2] - mx);
        float inv = 1.f / (e0 + e1 + e2);
        aw[0] = e0 * inv; aw[1] = e1 * inv; aw[2] = e2 * inv;
    }
    __syncthreads();
    xctx[t] = aw[0] * xin[t] + aw[1] * xin[128 + t] + aw[2] * xin[256 + t];
    __syncthreads();
    float sg = f1b[t], sb = f2b[t];
    for (int j = 0; j < 128; ++j) {
        float xj = xctx[j];
        sg += xj * f1w[t * 128 + j];
        sb += xj * f2w[t * 128 + j];
    }
    out[t]       = tanhf(sg);
    out[128 + t] = tanhf(sb);
}

extern "C" void kernel_launch(void* const* d_in, const int* in_sizes, int n_in,
                              void* d_out, int out_size, void* d_ws, size_t ws_size,
                              hipStream_t stream) {
    (void)in_sizes; (void)n_in; (void)out_size; (void)ws_size;

    const float* x[3]  = {(const float*)d_in[0], (const float*)d_in[1], (const float*)d_in[2]};
    const int*   ei[3] = {(const int*)d_in[3], (const int*)d_in[4], (const int*)d_in[5]};
    const float* cw[3] = {(const float*)d_in[6], (const float*)d_in[8], (const float*)d_in[10]};
    const float* cb[3] = {(const float*)d_in[7], (const float*)d_in[9], (const float*)d_in[11]};

    char* ws = (char*)d_ws;
    float*        hp     = (float*)ws;                       // 25,600,000
    unsigned int* binned = (unsigned int*)(ws + 25600000);   //  9,600,000
    int*          deg    = (int*)(ws + 35200000);            //    600,000
    int*          bHist  = (int*)(ws + 35800000);            //     16,384 (3*784*4 used)
    int*          bOff   = (int*)(ws + 35816384);            //     16,384
    int*          bCur   = (int*)(ws + 35832768);            //     16,384
    float*        g      = (float*)(ws + 35849152);          //      1,536

    hipMemsetAsync(bHist, 0, 3 * BSTRIDE * sizeof(int), stream);
    hipMemsetAsync(g, 0, 3 * DD * sizeof(float), stream);

    dim3 bin_grid(BIN_BLOCKS, 3);
    k_bcnt3 <<<bin_grid, 256, 0, stream>>>(ei[0], ei[1], ei[2], bHist);
    k_bscan3<<<3, 64, 0, stream>>>(bHist, bOff, bCur);
    k_bin3  <<<bin_grid, 256, 0, stream>>>(ei[0], ei[1], ei[2], bCur, binned);
    k_ndeg3 <<<dim3(NB, 3), 64, 0, stream>>>(binned, bOff, deg);

    for (int i = 0; i < 3; ++i) {
        k_gemmf  <<<(NN + 31) / 32, 256, 0, stream>>>(x[i], cw[i], deg + i * NN, hp, NN);
        k_bgather<<<NB, 256, 0, stream>>>(hp, binned + (long)i * NE,
                                          bOff + i * BSTRIDE, deg + i * NN, cb[i], g + i * DD);
    }
    k_head<<<1, 128, 0, stream>>>(g,
        (const float*)d_in[12], (const float*)d_in[13],
        (const float*)d_in[14], (const float*)d_in[15],
        (const float*)d_in[16], (const float*)d_in[17],
        (const float*)d_in[18], (const float*)d_in[19],
        (const float*)d_in[20], (const float*)d_in[21],
        (float*)d_out);
}

// Round 6
// 670.872 us; speedup vs baseline: 3.5643x; 3.5643x over previous
//
#include <hip/hip_runtime.h>

#define NN 50000
#define NE 800000
#define DD 128
#define NB 782          // buckets of 64 nodes: 782*64 = 50048 >= NN
#define BSTRIDE 784     // per-conv stride for bucket arrays
#define RPS 50016       // rowptr per-conv stride (>= NN+1)
#define CHUNK 8192      // edges per binning block
#define BIN_BLOCKS ((NE + CHUNK - 1) / CHUNK)   // 98

__device__ __forceinline__ int clampn(int v) {
    return v < 0 ? 0 : (v >= NN ? NN - 1 : v);
}

// ---- pass 1: per-bucket edge counts (LDS-aggregated) ----
__global__ __launch_bounds__(256) void k_bcnt3(const int* __restrict__ e0,
                                               const int* __restrict__ e1,
                                               const int* __restrict__ e2,
                                               int* __restrict__ bHist) {
    __shared__ int hist[NB];
    const int* ei = (blockIdx.y == 0 ? e0 : blockIdx.y == 1 ? e1 : e2);
    int t = threadIdx.x;
    for (int b = t; b < NB; b += 256) hist[b] = 0;
    __syncthreads();
    int base = blockIdx.x * CHUNK;
    int chunk = NE - base; if (chunk > CHUNK) chunk = CHUNK;
    for (int i = t; i < chunk; i += 256) {
        int d = clampn(ei[NE + base + i]);
        atomicAdd(&hist[d >> 6], 1);
    }
    __syncthreads();
    for (int b = t; b < NB; b += 256)
        if (hist[b]) atomicAdd(&bHist[blockIdx.y * BSTRIDE + b], hist[b]);
}

// ---- pass 2: scan bucket counts -> bOff (exclusive) and bCur ----
__global__ __launch_bounds__(64) void k_bscan3(const int* __restrict__ bHist,
                                               int* __restrict__ bOff,
                                               int* __restrict__ bCur) {
    int conv = blockIdx.x;
    int lane = threadIdx.x;
    const int PER = (NB + 63) / 64;   // 13
    int basei = lane * PER;
    int loc[PER];
    int s = 0;
    for (int j = 0; j < PER; ++j) {
        int b = basei + j;
        int h = (b < NB) ? bHist[conv * BSTRIDE + b] : 0;
        loc[j] = h; s += h;
    }
    int incl = s;
    for (int off = 1; off < 64; off <<= 1) {
        int u = __shfl_up(incl, off);
        if (lane >= off) incl += u;
    }
    int run = incl - s;
    for (int j = 0; j < PER; ++j) {
        int b = basei + j;
        if (b < NB) {
            bOff[conv * BSTRIDE + b] = run;
            bCur[conv * BSTRIDE + b] = run;
            run += loc[j];
        }
    }
    if (lane == 63) bOff[conv * BSTRIDE + NB] = incl;
}

// ---- pass 3: block-local counting sort by bucket, coalesced flush ----
__global__ __launch_bounds__(256) void k_bin3(const int* __restrict__ e0,
                                              const int* __restrict__ e1,
                                              const int* __restrict__ e2,
                                              int* __restrict__ bCur,
                                              unsigned int* __restrict__ binned) {
    __shared__ int hist[NB];
    __shared__ int off[NB];
    __shared__ int delta[NB];
    __shared__ unsigned int stage[CHUNK];
    __shared__ unsigned short sbuck[CHUNK];
    const int* ei = (blockIdx.y == 0 ? e0 : blockIdx.y == 1 ? e1 : e2);
    int conv = blockIdx.y;
    int t = threadIdx.x;
    int base = blockIdx.x * CHUNK;
    int chunk = NE - base; if (chunk > CHUNK) chunk = CHUNK;

    for (int b = t; b < NB; b += 256) hist[b] = 0;
    __syncthreads();
    for (int i = t; i < chunk; i += 256) {
        int d = clampn(ei[NE + base + i]);
        atomicAdd(&hist[d >> 6], 1);
    }
    __syncthreads();
    if (t < 64) {
        const int PER = (NB + 63) / 64;
        int basei = t * PER;
        int loc[(NB + 63) / 64];
        int s = 0;
        for (int j = 0; j < PER; ++j) {
            int b = basei + j;
            int h = (b < NB) ? hist[b] : 0;
            loc[j] = h; s += h;
        }
        int incl = s;
        for (int o = 1; o < 64; o <<= 1) {
            int u = __shfl_up(incl, o);
            if (t >= o) incl += u;
        }
        int run = incl - s;
        for (int j = 0; j < PER; ++j) {
            int b = basei + j;
            if (b < NB) { off[b] = run; run += loc[j]; }
        }
    }
    __syncthreads();
    for (int b = t; b < NB; b += 256) {
        if (hist[b]) {
            int gp = atomicAdd(&bCur[conv * BSTRIDE + b], hist[b]);
            delta[b] = gp - off[b];
        }
    }
    __syncthreads();
    for (int i = t; i < chunk; i += 256) {
        int s = clampn(ei[base + i]);
        int d = clampn(ei[NE + base + i]);
        int b = d >> 6;
        int slot = atomicAdd(&off[b], 1);
        stage[slot] = (unsigned int)s | ((unsigned int)(d & 63) << 16);
        sbuck[slot] = (unsigned short)b;
    }
    __syncthreads();
    for (int i = t; i < chunk; i += 256)
        binned[(long)conv * NE + delta[sbuck[i]] + i] = stage[i];
}

// ---- pass 4: within-bucket sort by node -> adj (src ids), deg, rowptr ----
__global__ __launch_bounds__(256) void k_sort3(const unsigned int* __restrict__ binned,
                                               const int* __restrict__ bOff,
                                               int* __restrict__ adj,
                                               int* __restrict__ deg,
                                               int* __restrict__ rowptr) {
    __shared__ int cnt[64];
    __shared__ int cur[64];
    int b = blockIdx.x, conv = blockIdx.y;
    int t = threadIdx.x;
    int beg = bOff[conv * BSTRIDE + b], end = bOff[conv * BSTRIDE + b + 1];
    const unsigned int* bp = binned + (long)conv * NE;
    if (t < 64) cnt[t] = 0;
    __syncthreads();
    for (int i = beg + t; i < end; i += 256)
        atomicAdd(&cnt[(bp[i] >> 16) & 63], 1);
    __syncthreads();
    if (t < 64) {
        int c = cnt[t];
        int incl = c;
        for (int o = 1; o < 64; o <<= 1) {
            int u = __shfl_up(incl, o);
            if (t >= o) incl += u;
        }
        cur[t] = beg + incl - c;            // global start for this node's run
        int v = b * 64 + t;
        if (v < NN) {
            deg[conv * NN + v] = c;
            rowptr[conv * RPS + v] = beg + incl - c;
            if (v == NN - 1) rowptr[conv * RPS + NN] = beg + incl;
        }
    }
    __syncthreads();
    for (int i = beg + t; i < end; i += 256) {
        unsigned int e = bp[i];
        int dl = (e >> 16) & 63;
        int pos = atomicAdd(&cur[dl], 1);
        adj[(long)conv * NE + pos] = (int)(e & 0xFFFFu);   // src fits in 16 bits (NN<65536)
    }
}

// ---- h' = (x @ W) * rsqrt(deg+1), all f32. 32 rows/block, 4x4 register tile ----
__global__ __launch_bounds__(256) void k_gemmf(const float* __restrict__ x,
                                               const float* __restrict__ W,
                                               const int* __restrict__ deg,
                                               float* __restrict__ hp, int n) {
    __shared__ float wl[DD * DD];
    __shared__ float xs[32 * DD];
    int tid = threadIdx.x;
    int base = blockIdx.x * 32;

    const float4* W4 = reinterpret_cast<const float4*>(W);
    float4* wl4 = reinterpret_cast<float4*>(wl);
    for (int it = 0; it < 16; ++it) wl4[it * 256 + tid] = W4[it * 256 + tid];
    float4* xs4 = reinterpret_cast<float4*>(xs);
    const float4* x4p = reinterpret_cast<const float4*>(x);
    for (int it = 0; it < 4; ++it) {
        int idx = it * 256 + tid;
        int row = idx >> 5, col4 = idx & 31;
        int r = base + row;
        xs4[idx] = (r < n) ? x4p[(long)r * 32 + col4] : float4{0.f, 0.f, 0.f, 0.f};
    }
    __syncthreads();

    int cg = tid & 31, rg = tid >> 5;
    int c0 = cg * 4;
    float acc[4][4] = {};
    for (int kk = 0; kk < 32; ++kk) {
        float4 xv[4], wv[4];
#pragma unroll
        for (int i = 0; i < 4; ++i)
            xv[i] = *reinterpret_cast<const float4*>(&xs[(rg * 4 + i) * DD + kk * 4]);
#pragma unroll
        for (int q = 0; q < 4; ++q)
            wv[q] = *reinterpret_cast<const float4*>(&wl[(kk * 4 + q) * DD + c0]);
#pragma unroll
        for (int i = 0; i < 4; ++i) {
#pragma unroll
            for (int j = 0; j < 4; ++j) {
                acc[i][j] += xv[i].x * (&wv[0].x)[j]
                           + xv[i].y * (&wv[1].x)[j]
                           + xv[i].z * (&wv[2].x)[j]
                           + xv[i].w * (&wv[3].x)[j];
            }
        }
    }
#pragma unroll
    for (int i = 0; i < 4; ++i) {
        int r = base + rg * 4 + i;
        if (r < n) {
            float dv = rsqrtf((float)(deg[r] + 1));
            float4 o = {acc[i][0] * dv, acc[i][1] * dv, acc[i][2] * dv, acc[i][3] * dv};
            *reinterpret_cast<float4*>(&hp[(long)r * DD + c0]) = o;
        }
    }
}

// ---- gather: one wave per node, prefetched adj + unroll-4 independent loads ----
__global__ __launch_bounds__(256) void k_gather2(const float* __restrict__ hp,
                                                 const int* __restrict__ rowptr,
                                                 const int* __restrict__ adj,
                                                 const int* __restrict__ deg,
                                                 const float* __restrict__ bias,
                                                 float* __restrict__ gout, int n) {
    int lane = threadIdx.x & 63;
    int wv = threadIdx.x >> 6;
    int gw = blockIdx.x * 4 + wv;
    int stride = gridDim.x * 4;
    const float2* hp2 = reinterpret_cast<const float2*>(hp);
    float2 b2 = reinterpret_cast<const float2*>(bias)[lane];
    float px = 0.f, py = 0.f;

    for (int v = gw; v < n; v += stride) {
        int beg = rowptr[v], end = rowptr[v + 1];
        float2 acc = hp2[(long)v * 64 + lane];           // self loop
        float2 a1 = {0.f, 0.f};
        int j = beg;
        while (j < end) {
            int rem = end - j;
            int cnt = rem < 64 ? rem : 64;
            int ent = (j + lane < end) ? adj[j + lane] : 0;
            int k = 0;
            for (; k + 4 <= cnt; k += 4) {
                int s0 = __shfl(ent, k);
                int s1 = __shfl(ent, k + 1);
                int s2 = __shfl(ent, k + 2);
                int s3 = __shfl(ent, k + 3);
                float2 t0 = hp2[(long)s0 * 64 + lane];
                float2 t1 = hp2[(long)s1 * 64 + lane];
                float2 t2 = hp2[(long)s2 * 64 + lane];
                float2 t3 = hp2[(long)s3 * 64 + lane];
                acc.x += t0.x + t1.x; acc.y += t0.y + t1.y;
                a1.x  += t2.x + t3.x; a1.y  += t2.y + t3.y;
            }
            for (; k < cnt; ++k) {
                int s = __shfl(ent, k);
                float2 t = hp2[(long)s * 64 + lane];
                acc.x += t.x; acc.y += t.y;
            }
            j += cnt;
        }
        acc.x += a1.x; acc.y += a1.y;
        float dv = rsqrtf((float)(deg[v] + 1));
        px += fmaxf(dv * acc.x + b2.x, 0.f);
        py += fmaxf(dv * acc.y + b2.y, 0.f);
    }
    __shared__ float red[4][DD];
    red[wv][lane * 2] = px;
    red[wv][lane * 2 + 1] = py;
    __syncthreads();
    int t = threadIdx.x;
    if (t < DD)
        unsafeAtomicAdd(&gout[t], red[0][t] + red[1][t] + red[2][t] + red[3][t]);
}

// ---- head MLP ----
__global__ __launch_bounds__(128) void k_head(const float* __restrict__ g,
    const float* __restrict__ w1, const float* __restrict__ b1,
    const float* __restrict__ w2, const float* __restrict__ b2,
    const float* __restrict__ w3, const float* __restrict__ b3,
    const float* __restrict__ f1w, const float* __restrict__ f1b,
    const float* __restrict__ f2w, const float* __restrict__ f2b,
    float* __restrict__ out) {
    __shared__ float xin[384], h1[128], h2[128], aw[3], xctx[128];
    int t = threadIdx.x;
    for (int i = t; i < 384; i += 128) xin[i] = g[i];
    __syncthreads();
    float s = b1[t];
    for (int j = 0; j < 384; ++j) s += xin[j] * w1[t * 384 + j];
    h1[t] = fmaxf(s, 0.f);
    __syncthreads();
    s = b2[t];
    for (int j = 0; j < 128; ++j) s += h1[j] * w2[t * 128 + j];
    h2[t] = fmaxf(s, 0.f);
    __syncthreads();
    if (t < 3) {
        float sl = b3[t];
        for (int j = 0; j < 128; ++j) sl += h2[j] * w3[t * 128 + j];
        aw[t] = sl;
    }
    __syncthreads();
    if (t == 0) {
        float mx = fmaxf(aw[0], fmaxf(aw[1], aw[2]));
        float e0 = expf(aw[0] - mx), e1 = expf(aw[1] - mx), e2 = expf(aw[2] - mx);
        float inv = 1.f / (e0 + e1 + e2);
        aw[0] = e0 * inv; aw[1] = e1 * inv; aw[2] = e2 * inv;
    }
    __syncthreads();
    xctx[t] = aw[0] * xin[t] + aw[1] * xin[128 + t] + aw[2] * xin[256 + t];
    __syncthreads();
    float sg = f1b[t], sb = f2b[t];
    for (int j = 0; j < 128; ++j) {
        float xj = xctx[j];
        sg += xj * f1w[t * 128 + j];
        sb += xj * f2w[t * 128 + j];
    }
    out[t]       = tanhf(sg);
    out[128 + t] = tanhf(sb);
}

extern "C" void kernel_launch(void* const* d_in, const int* in_sizes, int n_in,
                              void* d_out, int out_size, void* d_ws, size_t ws_size,
                              hipStream_t stream) {
    (void)in_sizes; (void)n_in; (void)out_size; (void)ws_size;

    const float* x[3]  = {(const float*)d_in[0], (const float*)d_in[1], (const float*)d_in[2]};
    const int*   ei[3] = {(const int*)d_in[3], (const int*)d_in[4], (const int*)d_in[5]};
    const float* cw[3] = {(const float*)d_in[6], (const float*)d_in[8], (const float*)d_in[10]};
    const float* cb[3] = {(const float*)d_in[7], (const float*)d_in[9], (const float*)d_in[11]};

    char* ws = (char*)d_ws;
    float*        hp     = (float*)ws;                       // 25,600,000
    unsigned int* binned = (unsigned int*)(ws + 25600000);   //  9,600,000
    int*          adj    = (int*)(ws + 35200000);            //  9,600,000
    int*          deg    = (int*)(ws + 44800000);            //    600,000
    int*          rowptr = (int*)(ws + 45400000);            //    600,192
    int*          bHist  = (int*)(ws + 46000192);            //      9,408
    int*          bOff   = (int*)(ws + 46009600);            //      9,420
    int*          bCur   = (int*)(ws + 46019020);            //      9,408
    float*        g      = (float*)(ws + 46028432);          //      1,536

    hipMemsetAsync(bHist, 0, 3 * BSTRIDE * sizeof(int), stream);
    hipMemsetAsync(g, 0, 3 * DD * sizeof(float), stream);

    dim3 bin_grid(BIN_BLOCKS, 3);
    k_bcnt3 <<<bin_grid, 256, 0, stream>>>(ei[0], ei[1], ei[2], bHist);
    k_bscan3<<<3, 64, 0, stream>>>(bHist, bOff, bCur);
    k_bin3  <<<bin_grid, 256, 0, stream>>>(ei[0], ei[1], ei[2], bCur, binned);
    k_sort3 <<<dim3(NB, 3), 256, 0, stream>>>(binned, bOff, adj, deg, rowptr);

    for (int i = 0; i < 3; ++i) {
        k_gemmf  <<<(NN + 31) / 32, 256, 0, stream>>>(x[i], cw[i], deg + i * NN, hp, NN);
        k_gather2<<<2048, 256, 0, stream>>>(hp, rowptr + i * RPS, adj + (long)i * NE,
                                            deg + i * NN, cb[i], g + i * DD, NN);
    }
    k_head<<<1, 128, 0, stream>>>(g,
        (const float*)d_in[12], (const float*)d_in[13],
        (const float*)d_in[14], (const float*)d_in[15],
        (const float*)d_in[16], (const float*)d_in[17],
        (const float*)d_in[18], (const float*)d_in[19],
        (const float*)d_in[20], (const float*)d_in[21],
        (float*)d_out);
}

// Round 7
// 602.946 us; speedup vs baseline: 3.9658x; 1.1127x over previous
//
#include <hip/hip_runtime.h>

#define NN 50000
#define NE 800000
#define DD 128
#define NB 782          // buckets of 64 nodes: 782*64 = 50048 >= NN
#define BSTRIDE 784     // per-conv stride for bucket arrays
#define RPS 50016       // rowptr per-conv stride (>= NN+1)
#define CHUNK 8192      // edges per binning block
#define BIN_BLOCKS ((NE + CHUNK - 1) / CHUNK)   // 98

__device__ __forceinline__ int clampn(int v) {
    return v < 0 ? 0 : (v >= NN ? NN - 1 : v);
}
__device__ __forceinline__ unsigned int f2bf(float f) {
    union { float f; unsigned int i; } v; v.f = f;
    unsigned int lsb = (v.i >> 16) & 1u;
    v.i += 0x7fffu + lsb;
    return (v.i >> 16) & 0xFFFFu;
}

// ---- pass 1: per-bucket edge counts (LDS-aggregated) ----
__global__ __launch_bounds__(256) void k_bcnt3(const int* __restrict__ e0,
                                               const int* __restrict__ e1,
                                               const int* __restrict__ e2,
                                               int* __restrict__ bHist) {
    __shared__ int hist[NB];
    const int* ei = (blockIdx.y == 0 ? e0 : blockIdx.y == 1 ? e1 : e2);
    int t = threadIdx.x;
    for (int b = t; b < NB; b += 256) hist[b] = 0;
    __syncthreads();
    int base = blockIdx.x * CHUNK;
    int chunk = NE - base; if (chunk > CHUNK) chunk = CHUNK;
    for (int i = t; i < chunk; i += 256) {
        int d = clampn(ei[NE + base + i]);
        atomicAdd(&hist[d >> 6], 1);
    }
    __syncthreads();
    for (int b = t; b < NB; b += 256)
        if (hist[b]) atomicAdd(&bHist[blockIdx.y * BSTRIDE + b], hist[b]);
}

// ---- pass 2: scan bucket counts -> bOff (exclusive) and bCur ----
__global__ __launch_bounds__(64) void k_bscan3(const int* __restrict__ bHist,
                                               int* __restrict__ bOff,
                                               int* __restrict__ bCur) {
    int conv = blockIdx.x;
    int lane = threadIdx.x;
    const int PER = (NB + 63) / 64;   // 13
    int basei = lane * PER;
    int loc[PER];
    int s = 0;
    for (int j = 0; j < PER; ++j) {
        int b = basei + j;
        int h = (b < NB) ? bHist[conv * BSTRIDE + b] : 0;
        loc[j] = h; s += h;
    }
    int incl = s;
    for (int off = 1; off < 64; off <<= 1) {
        int u = __shfl_up(incl, off);
        if (lane >= off) incl += u;
    }
    int run = incl - s;
    for (int j = 0; j < PER; ++j) {
        int b = basei + j;
        if (b < NB) {
            bOff[conv * BSTRIDE + b] = run;
            bCur[conv * BSTRIDE + b] = run;
            run += loc[j];
        }
    }
    if (lane == 63) bOff[conv * BSTRIDE + NB] = incl;
}

// ---- pass 3: block-local counting sort by bucket, coalesced flush ----
__global__ __launch_bounds__(256) void k_bin3(const int* __restrict__ e0,
                                              const int* __restrict__ e1,
                                              const int* __restrict__ e2,
                                              int* __restrict__ bCur,
                                              unsigned int* __restrict__ binned) {
    __shared__ int hist[NB];
    __shared__ int off[NB];
    __shared__ int delta[NB];
    __shared__ unsigned int stage[CHUNK];
    __shared__ unsigned short sbuck[CHUNK];
    const int* ei = (blockIdx.y == 0 ? e0 : blockIdx.y == 1 ? e1 : e2);
    int conv = blockIdx.y;
    int t = threadIdx.x;
    int base = blockIdx.x * CHUNK;
    int chunk = NE - base; if (chunk > CHUNK) chunk = CHUNK;

    for (int b = t; b < NB; b += 256) hist[b] = 0;
    __syncthreads();
    for (int i = t; i < chunk; i += 256) {
        int d = clampn(ei[NE + base + i]);
        atomicAdd(&hist[d >> 6], 1);
    }
    __syncthreads();
    if (t < 64) {
        const int PER = (NB + 63) / 64;
        int basei = t * PER;
        int loc[(NB + 63) / 64];
        int s = 0;
        for (int j = 0; j < PER; ++j) {
            int b = basei + j;
            int h = (b < NB) ? hist[b] : 0;
            loc[j] = h; s += h;
        }
        int incl = s;
        for (int o = 1; o < 64; o <<= 1) {
            int u = __shfl_up(incl, o);
            if (t >= o) incl += u;
        }
        int run = incl - s;
        for (int j = 0; j < PER; ++j) {
            int b = basei + j;
            if (b < NB) { off[b] = run; run += loc[j]; }
        }
    }
    __syncthreads();
    for (int b = t; b < NB; b += 256) {
        if (hist[b]) {
            int gp = atomicAdd(&bCur[conv * BSTRIDE + b], hist[b]);
            delta[b] = gp - off[b];
        }
    }
    __syncthreads();
    for (int i = t; i < chunk; i += 256) {
        int s = clampn(ei[base + i]);
        int d = clampn(ei[NE + base + i]);
        int b = d >> 6;
        int slot = atomicAdd(&off[b], 1);
        stage[slot] = (unsigned int)s | ((unsigned int)(d & 63) << 16);
        sbuck[slot] = (unsigned short)b;
    }
    __syncthreads();
    for (int i = t; i < chunk; i += 256)
        binned[(long)conv * NE + delta[sbuck[i]] + i] = stage[i];
}

// ---- pass 4: within-bucket sort by node -> adj (src ids), deg, rowptr ----
__global__ __launch_bounds__(256) void k_sort3(const unsigned int* __restrict__ binned,
                                               const int* __restrict__ bOff,
                                               int* __restrict__ adj,
                                               int* __restrict__ deg,
                                               int* __restrict__ rowptr) {
    __shared__ int cnt[64];
    __shared__ int cur[64];
    int b = blockIdx.x, conv = blockIdx.y;
    int t = threadIdx.x;
    int beg = bOff[conv * BSTRIDE + b], end = bOff[conv * BSTRIDE + b + 1];
    const unsigned int* bp = binned + (long)conv * NE;
    if (t < 64) cnt[t] = 0;
    __syncthreads();
    for (int i = beg + t; i < end; i += 256)
        atomicAdd(&cnt[(bp[i] >> 16) & 63], 1);
    __syncthreads();
    if (t < 64) {
        int c = cnt[t];
        int incl = c;
        for (int o = 1; o < 64; o <<= 1) {
            int u = __shfl_up(incl, o);
            if (t >= o) incl += u;
        }
        cur[t] = beg + incl - c;
        int v = b * 64 + t;
        if (v < NN) {
            deg[conv * NN + v] = c;
            rowptr[conv * RPS + v] = beg + incl - c;
            if (v == NN - 1) rowptr[conv * RPS + NN] = beg + incl;
        }
    }
    __syncthreads();
    for (int i = beg + t; i < end; i += 256) {
        unsigned int e = bp[i];
        int dl = (e >> 16) & 63;
        int pos = atomicAdd(&cur[dl], 1);
        adj[(long)conv * NE + pos] = (int)(e & 0xFFFFu);
    }
}

// ---- h' = (x @ W) * rsqrt(deg+1) -> bf16 packed (2 ch/u32) ----
__global__ __launch_bounds__(256) void k_gemmf(const float* __restrict__ x,
                                               const float* __restrict__ W,
                                               const int* __restrict__ deg,
                                               unsigned int* __restrict__ hpb, int n) {
    __shared__ float wl[DD * DD];
    __shared__ float xs[32 * DD];
    int tid = threadIdx.x;
    int base = blockIdx.x * 32;

    const float4* W4 = reinterpret_cast<const float4*>(W);
    float4* wl4 = reinterpret_cast<float4*>(wl);
    for (int it = 0; it < 16; ++it) wl4[it * 256 + tid] = W4[it * 256 + tid];
    float4* xs4 = reinterpret_cast<float4*>(xs);
    const float4* x4p = reinterpret_cast<const float4*>(x);
    for (int it = 0; it < 4; ++it) {
        int idx = it * 256 + tid;
        int row = idx >> 5, col4 = idx & 31;
        int r = base + row;
        xs4[idx] = (r < n) ? x4p[(long)r * 32 + col4] : float4{0.f, 0.f, 0.f, 0.f};
    }
    __syncthreads();

    int cg = tid & 31, rg = tid >> 5;
    int c0 = cg * 4;
    float acc[4][4] = {};
    for (int kk = 0; kk < 32; ++kk) {
        float4 xv[4], wv[4];
#pragma unroll
        for (int i = 0; i < 4; ++i)
            xv[i] = *reinterpret_cast<const float4*>(&xs[(rg * 4 + i) * DD + kk * 4]);
#pragma unroll
        for (int q = 0; q < 4; ++q)
            wv[q] = *reinterpret_cast<const float4*>(&wl[(kk * 4 + q) * DD + c0]);
#pragma unroll
        for (int i = 0; i < 4; ++i) {
#pragma unroll
            for (int j = 0; j < 4; ++j) {
                acc[i][j] += xv[i].x * (&wv[0].x)[j]
                           + xv[i].y * (&wv[1].x)[j]
                           + xv[i].z * (&wv[2].x)[j]
                           + xv[i].w * (&wv[3].x)[j];
            }
        }
    }
#pragma unroll
    for (int i = 0; i < 4; ++i) {
        int r = base + rg * 4 + i;
        if (r < n) {
            float dv = rsqrtf((float)(deg[r] + 1));
            unsigned int u0 = f2bf(acc[i][0] * dv) | (f2bf(acc[i][1] * dv) << 16);
            unsigned int u1 = f2bf(acc[i][2] * dv) | (f2bf(acc[i][3] * dv) << 16);
            uint2 o = {u0, u1};
            *reinterpret_cast<uint2*>(&hpb[(long)r * 64 + cg * 2]) = o;
        }
    }
}

// ---- gather: one wave per node, prefetched adj + unroll-8 bf16 row loads ----
__global__ __launch_bounds__(256) void k_gather2(const unsigned int* __restrict__ hpb,
                                                 const int* __restrict__ rowptr,
                                                 const int* __restrict__ adj,
                                                 const int* __restrict__ deg,
                                                 const float* __restrict__ bias,
                                                 float* __restrict__ gout, int n) {
    int lane = threadIdx.x & 63;
    int wv = threadIdx.x >> 6;
    int gw = blockIdx.x * 4 + wv;
    int stride = gridDim.x * 4;
    float2 b2 = reinterpret_cast<const float2*>(bias)[lane];
    float px = 0.f, py = 0.f;

    for (int v = gw; v < n; v += stride) {
        int beg = rowptr[v], end = rowptr[v + 1];
        unsigned int su = hpb[(long)v * 64 + lane];      // self loop
        float ax = __uint_as_float(su << 16);
        float ay = __uint_as_float(su & 0xFFFF0000u);
        float cx = 0.f, cy = 0.f;
        for (int j = beg; j < end; j += 64) {
            int cnt = end - j; if (cnt > 64) cnt = 64;
            int ent = (j + lane < end) ? adj[j + lane] : 0;
            int k = 0;
            for (; k + 8 <= cnt; k += 8) {
                int s0 = __shfl(ent, k + 0), s1 = __shfl(ent, k + 1);
                int s2 = __shfl(ent, k + 2), s3 = __shfl(ent, k + 3);
                int s4 = __shfl(ent, k + 4), s5 = __shfl(ent, k + 5);
                int s6 = __shfl(ent, k + 6), s7 = __shfl(ent, k + 7);
                unsigned int u0 = hpb[(long)s0 * 64 + lane];
                unsigned int u1 = hpb[(long)s1 * 64 + lane];
                unsigned int u2 = hpb[(long)s2 * 64 + lane];
                unsigned int u3 = hpb[(long)s3 * 64 + lane];
                unsigned int u4 = hpb[(long)s4 * 64 + lane];
                unsigned int u5 = hpb[(long)s5 * 64 + lane];
                unsigned int u6 = hpb[(long)s6 * 64 + lane];
                unsigned int u7 = hpb[(long)s7 * 64 + lane];
                ax += __uint_as_float(u0 << 16); ay += __uint_as_float(u0 & 0xFFFF0000u);
                cx += __uint_as_float(u1 << 16); cy += __uint_as_float(u1 & 0xFFFF0000u);
                ax += __uint_as_float(u2 << 16); ay += __uint_as_float(u2 & 0xFFFF0000u);
                cx += __uint_as_float(u3 << 16); cy += __uint_as_float(u3 & 0xFFFF0000u);
                ax += __uint_as_float(u4 << 16); ay += __uint_as_float(u4 & 0xFFFF0000u);
                cx += __uint_as_float(u5 << 16); cy += __uint_as_float(u5 & 0xFFFF0000u);
                ax += __uint_as_float(u6 << 16); ay += __uint_as_float(u6 & 0xFFFF0000u);
                cx += __uint_as_float(u7 << 16); cy += __uint_as_float(u7 & 0xFFFF0000u);
            }
            for (; k < cnt; ++k) {
                int s = __shfl(ent, k);
                unsigned int u = hpb[(long)s * 64 + lane];
                ax += __uint_as_float(u << 16);
                ay += __uint_as_float(u & 0xFFFF0000u);
            }
        }
        ax += cx; ay += cy;
        float dv = rsqrtf((float)(deg[v] + 1));
        px += fmaxf(dv * ax + b2.x, 0.f);
        py += fmaxf(dv * ay + b2.y, 0.f);
    }
    __shared__ float red[4][DD];
    red[wv][lane * 2] = px;
    red[wv][lane * 2 + 1] = py;
    __syncthreads();
    int t = threadIdx.x;
    if (t < DD)
        unsafeAtomicAdd(&gout[t], red[0][t] + red[1][t] + red[2][t] + red[3][t]);
}

// ---- head MLP ----
__global__ __launch_bounds__(128) void k_head(const float* __restrict__ g,
    const float* __restrict__ w1, const float* __restrict__ b1,
    const float* __restrict__ w2, const float* __restrict__ b2,
    const float* __restrict__ w3, const float* __restrict__ b3,
    const float* __restrict__ f1w, const float* __restrict__ f1b,
    const float* __restrict__ f2w, const float* __restrict__ f2b,
    float* __restrict__ out) {
    __shared__ float xin[384], h1[128], h2[128], aw[3], xctx[128];
    int t = threadIdx.x;
    for (int i = t; i < 384; i += 128) xin[i] = g[i];
    __syncthreads();
    float s = b1[t];
    for (int j = 0; j < 384; ++j) s += xin[j] * w1[t * 384 + j];
    h1[t] = fmaxf(s, 0.f);
    __syncthreads();
    s = b2[t];
    for (int j = 0; j < 128; ++j) s += h1[j] * w2[t * 128 + j];
    h2[t] = fmaxf(s, 0.f);
    __syncthreads();
    if (t < 3) {
        float sl = b3[t];
        for (int j = 0; j < 128; ++j) sl += h2[j] * w3[t * 128 + j];
        aw[t] = sl;
    }
    __syncthreads();
    if (t == 0) {
        float mx = fmaxf(aw[0], fmaxf(aw[1], aw[2]));
        float e0 = expf(aw[0] - mx), e1 = expf(aw[1] - mx), e2 = expf(aw[2] - mx);
        float inv = 1.f / (e0 + e1 + e2);
        aw[0] = e0 * inv; aw[1] = e1 * inv; aw[2] = e2 * inv;
    }
    __syncthreads();
    xctx[t] = aw[0] * xin[t] + aw[1] * xin[128 + t] + aw[2] * xin[256 + t];
    __syncthreads();
    float sg = f1b[t], sb = f2b[t];
    for (int j = 0; j < 128; ++j) {
        float xj = xctx[j];
        sg += xj * f1w[t * 128 + j];
        sb += xj * f2w[t * 128 + j];
    }
    out[t]       = tanhf(sg);
    out[128 + t] = tanhf(sb);
}

extern "C" void kernel_launch(void* const* d_in, const int* in_sizes, int n_in,
                              void* d_out, int out_size, void* d_ws, size_t ws_size,
                              hipStream_t stream) {
    (void)in_sizes; (void)n_in; (void)out_size; (void)ws_size;

    const float* x[3]  = {(const float*)d_in[0], (const float*)d_in[1], (const float*)d_in[2]};
    const int*   ei[3] = {(const int*)d_in[3], (const int*)d_in[4], (const int*)d_in[5]};
    const float* cw[3] = {(const float*)d_in[6], (const float*)d_in[8], (const float*)d_in[10]};
    const float* cb[3] = {(const float*)d_in[7], (const float*)d_in[9], (const float*)d_in[11]};

    char* ws = (char*)d_ws;
    unsigned int* hpb    = (unsigned int*)ws;                // 12,800,000 (NN*64*4)
    unsigned int* binned = (unsigned int*)(ws + 12800000);   //  9,600,000
    int*          adj    = (int*)(ws + 22400000);            //  9,600,000
    int*          deg    = (int*)(ws + 32000000);            //    600,000
    int*          rowptr = (int*)(ws + 32600000);            //    600,192
    int*          bHist  = (int*)(ws + 33200192);            //      9,408
    int*          bOff   = (int*)(ws + 33209600);            //      9,420
    int*          bCur   = (int*)(ws + 33219020);            //      9,408
    float*        g      = (float*)(ws + 33228428);          //      1,536

    hipMemsetAsync(bHist, 0, 3 * BSTRIDE * sizeof(int), stream);
    hipMemsetAsync(g, 0, 3 * DD * sizeof(float), stream);

    dim3 bin_grid(BIN_BLOCKS, 3);
    k_bcnt3 <<<bin_grid, 256, 0, stream>>>(ei[0], ei[1], ei[2], bHist);
    k_bscan3<<<3, 64, 0, stream>>>(bHist, bOff, bCur);
    k_bin3  <<<bin_grid, 256, 0, stream>>>(ei[0], ei[1], ei[2], bCur, binned);
    k_sort3 <<<dim3(NB, 3), 256, 0, stream>>>(binned, bOff, adj, deg, rowptr);

    for (int i = 0; i < 3; ++i) {
        k_gemmf  <<<(NN + 31) / 32, 256, 0, stream>>>(x[i], cw[i], deg + i * NN, hpb, NN);
        k_gather2<<<2048, 256, 0, stream>>>(hpb, rowptr + i * RPS, adj + (long)i * NE,
                                            deg + i * NN, cb[i], g + i * DD, NN);
    }
    k_head<<<1, 128, 0, stream>>>(g,
        (const float*)d_in[12], (const float*)d_in[13],
        (const float*)d_in[14], (const float*)d_in[15],
        (const float*)d_in[16], (const float*)d_in[17],
        (const float*)d_in[18], (const float*)d_in[19],
        (const float*)d_in[20], (const float*)d_in[21],
        (float*)d_out);
}

// Round 8
// 455.195 us; speedup vs baseline: 5.2531x; 1.3246x over previous
//
#include <hip/hip_runtime.h>

#define NN 50000
#define NE 800000
#define DD 128
#define NB 782          // buckets of 64 nodes
#define BSTRIDE 784
#define RPS 50016       // rowptr per-conv stride
#define CHUNK 4096
#define BIN_BLOCKS ((NE + CHUNK - 1) / CHUNK)   // 196

typedef float floatx4 __attribute__((ext_vector_type(4)));
typedef __bf16 bf16x8 __attribute__((ext_vector_type(8)));

__device__ __forceinline__ int clampn(int v) {
    return v < 0 ? 0 : (v >= NN ? NN - 1 : v);
}
__device__ __forceinline__ unsigned int f2bf(float f) {
    union { float f; unsigned int i; } v; v.f = f;
    unsigned int lsb = (v.i >> 16) & 1u;
    v.i += 0x7fffu + lsb;
    return (v.i >> 16) & 0xFFFFu;
}

// ---- pass 1: per-bucket edge counts ----
__global__ __launch_bounds__(256) void k_bcnt3(const int* __restrict__ e0,
                                               const int* __restrict__ e1,
                                               const int* __restrict__ e2,
                                               int* __restrict__ bHist) {
    __shared__ int hist[NB];
    const int* ei = (blockIdx.y == 0 ? e0 : blockIdx.y == 1 ? e1 : e2);
    int t = threadIdx.x;
    for (int b = t; b < NB; b += 256) hist[b] = 0;
    __syncthreads();
    int base = blockIdx.x * CHUNK;
    int chunk = NE - base; if (chunk > CHUNK) chunk = CHUNK;
    for (int i = t; i < chunk; i += 256) {
        int d = clampn(ei[NE + base + i]);
        atomicAdd(&hist[d >> 6], 1);
    }
    __syncthreads();
    for (int b = t; b < NB; b += 256)
        if (hist[b]) atomicAdd(&bHist[blockIdx.y * BSTRIDE + b], hist[b]);
}

// ---- pass 2: scan bucket counts -> bOff, bCur ----
__global__ __launch_bounds__(64) void k_bscan3(const int* __restrict__ bHist,
                                               int* __restrict__ bOff,
                                               int* __restrict__ bCur) {
    int conv = blockIdx.x;
    int lane = threadIdx.x;
    const int PER = (NB + 63) / 64;   // 13
    int basei = lane * PER;
    int loc[PER];
    int s = 0;
    for (int j = 0; j < PER; ++j) {
        int b = basei + j;
        int h = (b < NB) ? bHist[conv * BSTRIDE + b] : 0;
        loc[j] = h; s += h;
    }
    int incl = s;
    for (int off = 1; off < 64; off <<= 1) {
        int u = __shfl_up(incl, off);
        if (lane >= off) incl += u;
    }
    int run = incl - s;
    for (int j = 0; j < PER; ++j) {
        int b = basei + j;
        if (b < NB) {
            bOff[conv * BSTRIDE + b] = run;
            bCur[conv * BSTRIDE + b] = run;
            run += loc[j];
        }
    }
    if (lane == 63) bOff[conv * BSTRIDE + NB] = incl;
}

// ---- pass 3: block-local counting sort by bucket, coalesced flush ----
__global__ __launch_bounds__(256) void k_bin3(const int* __restrict__ e0,
                                              const int* __restrict__ e1,
                                              const int* __restrict__ e2,
                                              int* __restrict__ bCur,
                                              unsigned int* __restrict__ binned) {
    __shared__ int hist[NB];
    __shared__ int off[NB];
    __shared__ int delta[NB];
    __shared__ unsigned int stage[CHUNK];
    __shared__ unsigned short sbuck[CHUNK];
    const int* ei = (blockIdx.y == 0 ? e0 : blockIdx.y == 1 ? e1 : e2);
    int conv = blockIdx.y;
    int t = threadIdx.x;
    int base = blockIdx.x * CHUNK;
    int chunk = NE - base; if (chunk > CHUNK) chunk = CHUNK;

    for (int b = t; b < NB; b += 256) hist[b] = 0;
    __syncthreads();
    for (int i = t; i < chunk; i += 256) {
        int d = clampn(ei[NE + base + i]);
        atomicAdd(&hist[d >> 6], 1);
    }
    __syncthreads();
    if (t < 64) {
        const int PER = (NB + 63) / 64;
        int basei = t * PER;
        int loc[(NB + 63) / 64];
        int s = 0;
        for (int j = 0; j < PER; ++j) {
            int b = basei + j;
            int h = (b < NB) ? hist[b] : 0;
            loc[j] = h; s += h;
        }
        int incl = s;
        for (int o = 1; o < 64; o <<= 1) {
            int u = __shfl_up(incl, o);
            if (t >= o) incl += u;
        }
        int run = incl - s;
        for (int j = 0; j < PER; ++j) {
            int b = basei + j;
            if (b < NB) { off[b] = run; run += loc[j]; }
        }
    }
    __syncthreads();
    for (int b = t; b < NB; b += 256) {
        if (hist[b]) {
            int gp = atomicAdd(&bCur[conv * BSTRIDE + b], hist[b]);
            delta[b] = gp - off[b];
        }
    }
    __syncthreads();
    for (int i = t; i < chunk; i += 256) {
        int s = clampn(ei[base + i]);
        int d = clampn(ei[NE + base + i]);
        int b = d >> 6;
        int slot = atomicAdd(&off[b], 1);
        stage[slot] = (unsigned int)s | ((unsigned int)(d & 63) << 16);
        sbuck[slot] = (unsigned short)b;
    }
    __syncthreads();
    for (int i = t; i < chunk; i += 256)
        binned[(long)conv * NE + delta[sbuck[i]] + i] = stage[i];
}

// ---- pass 4: within-bucket sort by node -> adj, deg, rowptr ----
__global__ __launch_bounds__(256) void k_sort3(const unsigned int* __restrict__ binned,
                                               const int* __restrict__ bOff,
                                               int* __restrict__ adj,
                                               int* __restrict__ deg,
                                               int* __restrict__ rowptr) {
    __shared__ int cnt[64];
    __shared__ int cur[64];
    int b = blockIdx.x, conv = blockIdx.y;
    int t = threadIdx.x;
    int beg = bOff[conv * BSTRIDE + b], end = bOff[conv * BSTRIDE + b + 1];
    const unsigned int* bp = binned + (long)conv * NE;
    if (t < 64) cnt[t] = 0;
    __syncthreads();
    for (int i = beg + t; i < end; i += 256)
        atomicAdd(&cnt[(bp[i] >> 16) & 63], 1);
    __syncthreads();
    if (t < 64) {
        int c = cnt[t];
        int incl = c;
        for (int o = 1; o < 64; o <<= 1) {
            int u = __shfl_up(incl, o);
            if (t >= o) incl += u;
        }
        cur[t] = beg + incl - c;
        int v = b * 64 + t;
        if (v < NN) {
            deg[conv * NN + v] = c;
            rowptr[conv * RPS + v] = beg + incl - c;
            if (v == NN - 1) rowptr[conv * RPS + NN] = beg + incl;
        }
    }
    __syncthreads();
    for (int i = beg + t; i < end; i += 256) {
        unsigned int e = bp[i];
        int dl = (e >> 16) & 63;
        int pos = atomicAdd(&cur[dl], 1);
        adj[(long)conv * NE + pos] = (int)(e & 0xFFFFu);
    }
}

// ---- batched MFMA gemm: h' = bf16(x) @ bf16(W) * rsqrt(deg+1) -> bf16 ----
__global__ __launch_bounds__(256) void k_gemmb(
    const float* __restrict__ x0, const float* __restrict__ x1, const float* __restrict__ x2,
    const float* __restrict__ w0, const float* __restrict__ w1, const float* __restrict__ w2,
    const int* __restrict__ deg, unsigned short* __restrict__ hpbs, int n) {
    int conv = blockIdx.y;
    const float* x = conv == 0 ? x0 : conv == 1 ? x1 : x2;
    const float* W = conv == 0 ? w0 : conv == 1 ? w1 : w2;
    const int* dg = deg + conv * NN;
    unsigned short* hp = hpbs + (size_t)conv * NN * DD;

    __shared__ __align__(16) unsigned short wt[128 * 136];  // W^T bf16: wt[c*136+k]
    __shared__ __align__(16) unsigned short xb[64 * 136];   // x rows bf16
    int tid = threadIdx.x;
    int base = blockIdx.x * 64;

    for (int it = 0; it < 64; ++it) {
        int idx = it * 256 + tid;            // idx = k*128 + c
        int k = idx >> 7, c = idx & 127;
        wt[c * 136 + k] = (unsigned short)f2bf(W[idx]);
    }
    for (int it = 0; it < 32; ++it) {
        int idx = it * 256 + tid;            // idx = row*128 + c
        int row = idx >> 7, c = idx & 127;
        int r = base + row;
        float v = (r < n) ? x[(long)r * DD + c] : 0.f;
        xb[row * 136 + c] = (unsigned short)f2bf(v);
    }
    __syncthreads();

    int wave = tid >> 6, lane = tid & 63;
    int quad = lane >> 4, m = lane & 15;
    int rowb = wave * 16;

    bf16x8 a[4];
#pragma unroll
    for (int s = 0; s < 4; ++s)
        a[s] = *reinterpret_cast<const bf16x8*>(&xb[(rowb + m) * 136 + s * 32 + quad * 8]);

    floatx4 acc[8] = {};
#pragma unroll
    for (int j = 0; j < 8; ++j) {
#pragma unroll
        for (int s = 0; s < 4; ++s) {
            bf16x8 b = *reinterpret_cast<const bf16x8*>(&wt[(j * 16 + m) * 136 + s * 32 + quad * 8]);
            acc[j] = __builtin_amdgcn_mfma_f32_16x16x32_bf16(a[s], b, acc[j], 0, 0, 0);
        }
    }
#pragma unroll
    for (int r = 0; r < 4; ++r) {
        int rr = base + rowb + quad * 4 + r;
        if (rr < n) {
            float dv = rsqrtf((float)(dg[rr] + 1));
#pragma unroll
            for (int j = 0; j < 8; ++j)
                hp[(long)rr * DD + j * 16 + m] = (unsigned short)f2bf(acc[j][r] * dv);
        }
    }
}

// ---- batched gather: one wave per node, 16 loads in flight ----
__global__ __launch_bounds__(256) void k_gather3(const unsigned int* __restrict__ hpb0,
                                                 const int* __restrict__ rowptr,
                                                 const int* __restrict__ adj,
                                                 const int* __restrict__ deg,
                                                 const float* __restrict__ cb0,
                                                 const float* __restrict__ cb1,
                                                 const float* __restrict__ cb2,
                                                 float* __restrict__ gout, int n) {
    int conv = blockIdx.y;
    const unsigned int* hpb = hpb0 + (size_t)conv * NN * 64;
    const int* rp = rowptr + conv * RPS;
    const int* ad = adj + (long)conv * NE;
    const int* dg = deg + conv * NN;
    const float* bias = conv == 0 ? cb0 : conv == 1 ? cb1 : cb2;
    float* go = gout + conv * DD;

    int lane = threadIdx.x & 63;
    int wv = threadIdx.x >> 6;
    int gw = blockIdx.x * 4 + wv;
    int stride = gridDim.x * 4;
    float2 b2 = reinterpret_cast<const float2*>(bias)[lane];
    float px = 0.f, py = 0.f;

    for (int v = gw; v < n; v += stride) {
        int beg = rp[v], end = rp[v + 1];
        unsigned int su = hpb[(long)v * 64 + lane];
        float ax = __uint_as_float(su << 16);
        float ay = __uint_as_float(su & 0xFFFF0000u);
        float cx = 0.f, cy = 0.f;
        for (int j = beg; j < end; j += 64) {
            int cnt = end - j; if (cnt > 64) cnt = 64;
            int ent = (j + lane < end) ? ad[j + lane] : 0;
            int k = 0;
            for (; k + 16 <= cnt; k += 16) {
                unsigned int u[16];
#pragma unroll
                for (int q = 0; q < 16; ++q) {
                    int s = __shfl(ent, k + q);
                    u[q] = hpb[(long)s * 64 + lane];
                }
#pragma unroll
                for (int q = 0; q < 16; q += 2) {
                    ax += __uint_as_float(u[q] << 16);
                    ay += __uint_as_float(u[q] & 0xFFFF0000u);
                    cx += __uint_as_float(u[q + 1] << 16);
                    cy += __uint_as_float(u[q + 1] & 0xFFFF0000u);
                }
            }
            for (; k + 4 <= cnt; k += 4) {
                int s0 = __shfl(ent, k), s1 = __shfl(ent, k + 1);
                int s2 = __shfl(ent, k + 2), s3 = __shfl(ent, k + 3);
                unsigned int u0 = hpb[(long)s0 * 64 + lane];
                unsigned int u1 = hpb[(long)s1 * 64 + lane];
                unsigned int u2 = hpb[(long)s2 * 64 + lane];
                unsigned int u3 = hpb[(long)s3 * 64 + lane];
                ax += __uint_as_float(u0 << 16); ay += __uint_as_float(u0 & 0xFFFF0000u);
                cx += __uint_as_float(u1 << 16); cy += __uint_as_float(u1 & 0xFFFF0000u);
                ax += __uint_as_float(u2 << 16); ay += __uint_as_float(u2 & 0xFFFF0000u);
                cx += __uint_as_float(u3 << 16); cy += __uint_as_float(u3 & 0xFFFF0000u);
            }
            for (; k < cnt; ++k) {
                int s = __shfl(ent, k);
                unsigned int u = hpb[(long)s * 64 + lane];
                ax += __uint_as_float(u << 16);
                ay += __uint_as_float(u & 0xFFFF0000u);
            }
        }
        ax += cx; ay += cy;
        float dv = rsqrtf((float)(dg[v] + 1));
        px += fmaxf(dv * ax + b2.x, 0.f);
        py += fmaxf(dv * ay + b2.y, 0.f);
    }
    __shared__ float red[4][DD];
    red[wv][lane * 2] = px;
    red[wv][lane * 2 + 1] = py;
    __syncthreads();
    int t = threadIdx.x;
    if (t < DD)
        unsafeAtomicAdd(&go[t], red[0][t] + red[1][t] + red[2][t] + red[3][t]);
}

// ---- head MLP ----
__global__ __launch_bounds__(128) void k_head(const float* __restrict__ g,
    const float* __restrict__ w1, const float* __restrict__ b1,
    const float* __restrict__ w2, const float* __restrict__ b2,
    const float* __restrict__ w3, const float* __restrict__ b3,
    const float* __restrict__ f1w, const float* __restrict__ f1b,
    const float* __restrict__ f2w, const float* __restrict__ f2b,
    float* __restrict__ out) {
    __shared__ float xin[384], h1[128], h2[128], aw[3], xctx[128];
    int t = threadIdx.x;
    for (int i = t; i < 384; i += 128) xin[i] = g[i];
    __syncthreads();
    float s = b1[t];
    for (int j = 0; j < 384; ++j) s += xin[j] * w1[t * 384 + j];
    h1[t] = fmaxf(s, 0.f);
    __syncthreads();
    s = b2[t];
    for (int j = 0; j < 128; ++j) s += h1[j] * w2[t * 128 + j];
    h2[t] = fmaxf(s, 0.f);
    __syncthreads();
    if (t < 3) {
        float sl = b3[t];
        for (int j = 0; j < 128; ++j) sl += h2[j] * w3[t * 128 + j];
        aw[t] = sl;
    }
    __syncthreads();
    if (t == 0) {
        float mx = fmaxf(aw[0], fmaxf(aw[1], aw[2]));
        float e0 = expf(aw[0] - mx), e1 = expf(aw[1] - mx), e2 = expf(aw[2] - mx);
        float inv = 1.f / (e0 + e1 + e2);
        aw[0] = e0 * inv; aw[1] = e1 * inv; aw[2] = e2 * inv;
    }
    __syncthreads();
    xctx[t] = aw[0] * xin[t] + aw[1] * xin[128 + t] + aw[2] * xin[256 + t];
    __syncthreads();
    float sg = f1b[t], sb = f2b[t];
    for (int j = 0; j < 128; ++j) {
        float xj = xctx[j];
        sg += xj * f1w[t * 128 + j];
        sb += xj * f2w[t * 128 + j];
    }
    out[t]       = tanhf(sg);
    out[128 + t] = tanhf(sb);
}

extern "C" void kernel_launch(void* const* d_in, const int* in_sizes, int n_in,
                              void* d_out, int out_size, void* d_ws, size_t ws_size,
                              hipStream_t stream) {
    (void)in_sizes; (void)n_in; (void)out_size; (void)ws_size;

    const float* x[3]  = {(const float*)d_in[0], (const float*)d_in[1], (const float*)d_in[2]};
    const int*   ei[3] = {(const int*)d_in[3], (const int*)d_in[4], (const int*)d_in[5]};
    const float* cw[3] = {(const float*)d_in[6], (const float*)d_in[8], (const float*)d_in[10]};
    const float* cb[3] = {(const float*)d_in[7], (const float*)d_in[9], (const float*)d_in[11]};

    // layout (binned overlaid by hpb: binned dead after k_sort3)
    char* ws = (char*)d_ws;
    int*          adj    = (int*)ws;                         //  9,600,000
    int*          deg    = (int*)(ws + 9600000);             //    600,000
    int*          rowptr = (int*)(ws + 10200000);            //    600,192
    int*          bHist  = (int*)(ws + 10800192);            //      9,408
    int*          bOff   = (int*)(ws + 10809600);            //      9,408
    int*          bCur   = (int*)(ws + 10819008);            //      9,408
    float*        g      = (float*)(ws + 10828416);          //      1,536
    char*         uni    = ws + 10830080;                    // union region
    unsigned int* binned = (unsigned int*)uni;               //  9,600,000
    unsigned int* hpb    = (unsigned int*)uni;               // 38,400,000 (3 x 12.8 MB)

    hipMemsetAsync(bHist, 0, 3 * BSTRIDE * sizeof(int), stream);
    hipMemsetAsync(g, 0, 3 * DD * sizeof(float), stream);

    dim3 bin_grid(BIN_BLOCKS, 3);
    k_bcnt3 <<<bin_grid, 256, 0, stream>>>(ei[0], ei[1], ei[2], bHist);
    k_bscan3<<<3, 64, 0, stream>>>(bHist, bOff, bCur);
    k_bin3  <<<bin_grid, 256, 0, stream>>>(ei[0], ei[1], ei[2], bCur, binned);
    k_sort3 <<<dim3(NB, 3), 256, 0, stream>>>(binned, bOff, adj, deg, rowptr);

    k_gemmb<<<dim3(NB, 3), 256, 0, stream>>>(x[0], x[1], x[2], cw[0], cw[1], cw[2],
                                             deg, (unsigned short*)hpb, NN);
    k_gather3<<<dim3(2048, 3), 256, 0, stream>>>(hpb, rowptr, adj, deg,
                                                 cb[0], cb[1], cb[2], g, NN);

    k_head<<<1, 128, 0, stream>>>(g,
        (const float*)d_in[12], (const float*)d_in[13],
        (const float*)d_in[14], (const float*)d_in[15],
        (const float*)d_in[16], (const float*)d_in[17],
        (const float*)d_in[18], (const float*)d_in[19],
        (const float*)d_in[20], (const float*)d_in[21],
        (float*)d_out);
}

// Round 9
// 412.165 us; speedup vs baseline: 5.8015x; 1.1044x over previous
//
#include <hip/hip_runtime.h>

#define NN 50000
#define NE 800000
#define DD 128
#define NB 782          // buckets of 64 nodes
#define BSTRIDE 784
#define RPS 50016       // rowptr per-conv stride
#define CHUNK 4096
#define BIN_BLOCKS ((NE + CHUNK - 1) / CHUNK)   // 196

typedef float floatx4 __attribute__((ext_vector_type(4)));
typedef __bf16 bf16x8 __attribute__((ext_vector_type(8)));

__device__ __forceinline__ int clampn(int v) {
    return v < 0 ? 0 : (v >= NN ? NN - 1 : v);
}
__device__ __forceinline__ unsigned int f2bf(float f) {
    union { float f; unsigned int i; } v; v.f = f;
    unsigned int lsb = (v.i >> 16) & 1u;
    v.i += 0x7fffu + lsb;
    return (v.i >> 16) & 0xFFFFu;
}

// ---- pass 1: per-bucket edge counts ----
__global__ __launch_bounds__(256) void k_bcnt3(const int* __restrict__ e0,
                                               const int* __restrict__ e1,
                                               const int* __restrict__ e2,
                                               int* __restrict__ bHist) {
    __shared__ int hist[NB];
    const int* ei = (blockIdx.y == 0 ? e0 : blockIdx.y == 1 ? e1 : e2);
    int t = threadIdx.x;
    for (int b = t; b < NB; b += 256) hist[b] = 0;
    __syncthreads();
    int base = blockIdx.x * CHUNK;
    int chunk = NE - base; if (chunk > CHUNK) chunk = CHUNK;
    for (int i = t; i < chunk; i += 256) {
        int d = clampn(ei[NE + base + i]);
        atomicAdd(&hist[d >> 6], 1);
    }
    __syncthreads();
    for (int b = t; b < NB; b += 256)
        if (hist[b]) atomicAdd(&bHist[blockIdx.y * BSTRIDE + b], hist[b]);
}

// ---- pass 2: scan bucket counts -> bOff, bCur ----
__global__ __launch_bounds__(64) void k_bscan3(const int* __restrict__ bHist,
                                               int* __restrict__ bOff,
                                               int* __restrict__ bCur) {
    int conv = blockIdx.x;
    int lane = threadIdx.x;
    const int PER = (NB + 63) / 64;   // 13
    int basei = lane * PER;
    int loc[PER];
    int s = 0;
    for (int j = 0; j < PER; ++j) {
        int b = basei + j;
        int h = (b < NB) ? bHist[conv * BSTRIDE + b] : 0;
        loc[j] = h; s += h;
    }
    int incl = s;
    for (int off = 1; off < 64; off <<= 1) {
        int u = __shfl_up(incl, off);
        if (lane >= off) incl += u;
    }
    int run = incl - s;
    for (int j = 0; j < PER; ++j) {
        int b = basei + j;
        if (b < NB) {
            bOff[conv * BSTRIDE + b] = run;
            bCur[conv * BSTRIDE + b] = run;
            run += loc[j];
        }
    }
    if (lane == 63) bOff[conv * BSTRIDE + NB] = incl;
}

// ---- pass 3: block-local counting sort by bucket, coalesced flush ----
__global__ __launch_bounds__(256) void k_bin3(const int* __restrict__ e0,
                                              const int* __restrict__ e1,
                                              const int* __restrict__ e2,
                                              int* __restrict__ bCur,
                                              unsigned int* __restrict__ binned) {
    __shared__ int hist[NB];
    __shared__ int off[NB];
    __shared__ int delta[NB];
    __shared__ unsigned int stage[CHUNK];
    __shared__ unsigned short sbuck[CHUNK];
    const int* ei = (blockIdx.y == 0 ? e0 : blockIdx.y == 1 ? e1 : e2);
    int conv = blockIdx.y;
    int t = threadIdx.x;
    int base = blockIdx.x * CHUNK;
    int chunk = NE - base; if (chunk > CHUNK) chunk = CHUNK;

    for (int b = t; b < NB; b += 256) hist[b] = 0;
    __syncthreads();
    for (int i = t; i < chunk; i += 256) {
        int d = clampn(ei[NE + base + i]);
        atomicAdd(&hist[d >> 6], 1);
    }
    __syncthreads();
    if (t < 64) {
        const int PER = (NB + 63) / 64;
        int basei = t * PER;
        int loc[(NB + 63) / 64];
        int s = 0;
        for (int j = 0; j < PER; ++j) {
            int b = basei + j;
            int h = (b < NB) ? hist[b] : 0;
            loc[j] = h; s += h;
        }
        int incl = s;
        for (int o = 1; o < 64; o <<= 1) {
            int u = __shfl_up(incl, o);
            if (t >= o) incl += u;
        }
        int run = incl - s;
        for (int j = 0; j < PER; ++j) {
            int b = basei + j;
            if (b < NB) { off[b] = run; run += loc[j]; }
        }
    }
    __syncthreads();
    for (int b = t; b < NB; b += 256) {
        if (hist[b]) {
            int gp = atomicAdd(&bCur[conv * BSTRIDE + b], hist[b]);
            delta[b] = gp - off[b];
        }
    }
    __syncthreads();
    for (int i = t; i < chunk; i += 256) {
        int s = clampn(ei[base + i]);
        int d = clampn(ei[NE + base + i]);
        int b = d >> 6;
        int slot = atomicAdd(&off[b], 1);
        stage[slot] = (unsigned int)s | ((unsigned int)(d & 63) << 16);
        sbuck[slot] = (unsigned short)b;
    }
    __syncthreads();
    for (int i = t; i < chunk; i += 256)
        binned[(long)conv * NE + delta[sbuck[i]] + i] = stage[i];
}

// ---- pass 4: within-bucket sort by node -> adj, deg, rowptr ----
__global__ __launch_bounds__(256) void k_sort3(const unsigned int* __restrict__ binned,
                                               const int* __restrict__ bOff,
                                               int* __restrict__ adj,
                                               int* __restrict__ deg,
                                               int* __restrict__ rowptr) {
    __shared__ int cnt[64];
    __shared__ int cur[64];
    int b = blockIdx.x, conv = blockIdx.y;
    int t = threadIdx.x;
    int beg = bOff[conv * BSTRIDE + b], end = bOff[conv * BSTRIDE + b + 1];
    const unsigned int* bp = binned + (long)conv * NE;
    if (t < 64) cnt[t] = 0;
    __syncthreads();
    for (int i = beg + t; i < end; i += 256)
        atomicAdd(&cnt[(bp[i] >> 16) & 63], 1);
    __syncthreads();
    if (t < 64) {
        int c = cnt[t];
        int incl = c;
        for (int o = 1; o < 64; o <<= 1) {
            int u = __shfl_up(incl, o);
            if (t >= o) incl += u;
        }
        cur[t] = beg + incl - c;
        int v = b * 64 + t;
        if (v < NN) {
            deg[conv * NN + v] = c;
            rowptr[conv * RPS + v] = beg + incl - c;
            if (v == NN - 1) rowptr[conv * RPS + NN] = beg + incl;
        }
    }
    __syncthreads();
    for (int i = beg + t; i < end; i += 256) {
        unsigned int e = bp[i];
        int dl = (e >> 16) & 63;
        int pos = atomicAdd(&cur[dl], 1);
        adj[(long)conv * NE + pos] = (int)(e & 0xFFFFu);
    }
}

// ---- W^T bf16 precompute: wtg[conv][c*128+k] = bf16(W[k][c]) ----
__global__ __launch_bounds__(256) void k_wt3(const float* __restrict__ w0,
                                             const float* __restrict__ w1,
                                             const float* __restrict__ w2,
                                             unsigned short* __restrict__ wtg) {
    int conv = blockIdx.x;
    const float* W = conv == 0 ? w0 : conv == 1 ? w1 : w2;
    unsigned short* o = wtg + conv * DD * DD;
    for (int idx = threadIdx.x; idx < DD * DD; idx += 256) {
        int k = idx >> 7, c = idx & 127;
        o[c * DD + k] = (unsigned short)f2bf(W[idx]);
    }
}

// ---- batched MFMA gemm: h' = bf16(x) @ bf16(W) * rsqrt(deg+1) -> bf16 ----
__global__ __launch_bounds__(256) void k_gemmb(
    const float* __restrict__ x0, const float* __restrict__ x1, const float* __restrict__ x2,
    const unsigned short* __restrict__ wtg,
    const int* __restrict__ deg, unsigned short* __restrict__ hpbs, int n) {
    int conv = blockIdx.y;
    const float* x = conv == 0 ? x0 : conv == 1 ? x1 : x2;
    const int* dg = deg + conv * NN;
    unsigned short* hp = hpbs + (size_t)conv * NN * DD;

    __shared__ __align__(16) unsigned short wt[128 * 136];  // W^T bf16, padded
    __shared__ __align__(16) unsigned short xb[64 * 136];   // x rows bf16, padded
    int tid = threadIdx.x;
    int base = blockIdx.x * 64;

    // stage W^T: 2048 uint4 chunks; chunk -> (c = chunk>>4, g = chunk&15)
    const uint4* wg = reinterpret_cast<const uint4*>(wtg + conv * DD * DD);
#pragma unroll
    for (int it = 0; it < 8; ++it) {
        int chunk = it * 256 + tid;
        int c = chunk >> 4, gq = chunk & 15;
        *reinterpret_cast<uint4*>(&wt[c * 136 + gq * 8]) = wg[chunk];
    }
    // stage x: 2048 float4 chunks -> bf16 pairs
    const float4* x4p = reinterpret_cast<const float4*>(x);
#pragma unroll
    for (int it = 0; it < 8; ++it) {
        int idx = it * 256 + tid;
        int row = idx >> 5, c4 = idx & 31;
        int r = base + row;
        float4 v = (r < n) ? x4p[(long)r * 32 + c4] : float4{0.f, 0.f, 0.f, 0.f};
        unsigned int p0 = f2bf(v.x) | (f2bf(v.y) << 16);
        unsigned int p1 = f2bf(v.z) | (f2bf(v.w) << 16);
        uint2 pv = {p0, p1};
        *reinterpret_cast<uint2*>(&xb[row * 136 + c4 * 4]) = pv;
    }
    __syncthreads();

    int wave = tid >> 6, lane = tid & 63;
    int quad = lane >> 4, m = lane & 15;
    int rowb = wave * 16;

    bf16x8 a[4];
#pragma unroll
    for (int s = 0; s < 4; ++s)
        a[s] = *reinterpret_cast<const bf16x8*>(&xb[(rowb + m) * 136 + s * 32 + quad * 8]);

    floatx4 acc[8] = {};
#pragma unroll
    for (int j = 0; j < 8; ++j) {
#pragma unroll
        for (int s = 0; s < 4; ++s) {
            bf16x8 b = *reinterpret_cast<const bf16x8*>(&wt[(j * 16 + m) * 136 + s * 32 + quad * 8]);
            acc[j] = __builtin_amdgcn_mfma_f32_16x16x32_bf16(a[s], b, acc[j], 0, 0, 0);
        }
    }
#pragma unroll
    for (int r = 0; r < 4; ++r) {
        int rr = base + rowb + quad * 4 + r;
        if (rr < n) {
            float dv = rsqrtf((float)(dg[rr] + 1));
#pragma unroll
            for (int j = 0; j < 8; ++j)
                hp[(long)rr * DD + j * 16 + m] = (unsigned short)f2bf(acc[j][r] * dv);
        }
    }
}

// ---- batched gather: wave/node, readlane broadcast, always-16 in flight ----
__global__ __launch_bounds__(256) void k_gather3(const unsigned int* __restrict__ hpb0,
                                                 const int* __restrict__ rowptr,
                                                 const int* __restrict__ adj,
                                                 const int* __restrict__ deg,
                                                 const float* __restrict__ cb0,
                                                 const float* __restrict__ cb1,
                                                 const float* __restrict__ cb2,
                                                 float* __restrict__ gout, int n) {
    int conv = blockIdx.y;
    const unsigned int* hpb = hpb0 + (size_t)conv * NN * 64;
    const int* rp = rowptr + conv * RPS;
    const int* ad = adj + (long)conv * NE;
    const int* dg = deg + conv * NN;
    const float* bias = conv == 0 ? cb0 : conv == 1 ? cb1 : cb2;
    float* go = gout + conv * DD;

    int lane = threadIdx.x & 63;
    int wv = threadIdx.x >> 6;
    int gw = blockIdx.x * 4 + wv;
    int stride = gridDim.x * 4;
    float2 b2 = reinterpret_cast<const float2*>(bias)[lane];
    float px = 0.f, py = 0.f;

    for (int v = gw; v < n; v += stride) {
        int beg = rp[v], end = rp[v + 1];
        unsigned int su = hpb[(long)v * 64 + lane];
        float ax = __uint_as_float(su << 16);
        float ay = __uint_as_float(su & 0xFFFF0000u);
        float cx = 0.f, cy = 0.f;
        for (int j = beg; j < end; j += 64) {
            int cnt = end - j; if (cnt > 64) cnt = 64;
            int ai = j + lane; if (ai > end - 1) ai = end - 1;
            int ent = ad[ai];
            int k = 0;
            // full batches: 16 loads in flight, no masking
            for (; k + 16 <= cnt; k += 16) {
                unsigned int u[16];
#pragma unroll
                for (int q = 0; q < 16; ++q) {
                    int s = __builtin_amdgcn_readlane(ent, k + q);
                    u[q] = hpb[(long)s * 64 + lane];
                }
#pragma unroll
                for (int q = 0; q < 16; q += 2) {
                    ax += __uint_as_float(u[q] << 16);
                    ay += __uint_as_float(u[q] & 0xFFFF0000u);
                    cx += __uint_as_float(u[q + 1] << 16);
                    cy += __uint_as_float(u[q + 1] & 0xFFFF0000u);
                }
            }
            // one masked batch of 16 covers the remainder (dup rows hit L1)
            if (k < cnt) {
                unsigned int u[16];
#pragma unroll
                for (int q = 0; q < 16; ++q) {
                    int idx = k + q; if (idx > cnt - 1) idx = cnt - 1;
                    int s = __builtin_amdgcn_readlane(ent, idx);
                    u[q] = hpb[(long)s * 64 + lane];
                }
#pragma unroll
                for (int q = 0; q < 16; ++q)
                    if (k + q >= cnt) u[q] = 0u;
#pragma unroll
                for (int q = 0; q < 16; q += 2) {
                    ax += __uint_as_float(u[q] << 16);
                    ay += __uint_as_float(u[q] & 0xFFFF0000u);
                    cx += __uint_as_float(u[q + 1] << 16);
                    cy += __uint_as_float(u[q + 1] & 0xFFFF0000u);
                }
            }
        }
        ax += cx; ay += cy;
        float dv = rsqrtf((float)(dg[v] + 1));
        px += fmaxf(dv * ax + b2.x, 0.f);
        py += fmaxf(dv * ay + b2.y, 0.f);
    }
    __shared__ float red[4][DD];
    red[wv][lane * 2] = px;
    red[wv][lane * 2 + 1] = py;
    __syncthreads();
    int t = threadIdx.x;
    if (t < DD)
        unsafeAtomicAdd(&go[t], red[0][t] + red[1][t] + red[2][t] + red[3][t]);
}

// ---- head MLP ----
__global__ __launch_bounds__(128) void k_head(const float* __restrict__ g,
    const float* __restrict__ w1, const float* __restrict__ b1,
    const float* __restrict__ w2, const float* __restrict__ b2,
    const float* __restrict__ w3, const float* __restrict__ b3,
    const float* __restrict__ f1w, const float* __restrict__ f1b,
    const float* __restrict__ f2w, const float* __restrict__ f2b,
    float* __restrict__ out) {
    __shared__ float xin[384], h1[128], h2[128], aw[3], xctx[128];
    int t = threadIdx.x;
    for (int i = t; i < 384; i += 128) xin[i] = g[i];
    __syncthreads();
    float s = b1[t];
    for (int j = 0; j < 384; ++j) s += xin[j] * w1[t * 384 + j];
    h1[t] = fmaxf(s, 0.f);
    __syncthreads();
    s = b2[t];
    for (int j = 0; j < 128; ++j) s += h1[j] * w2[t * 128 + j];
    h2[t] = fmaxf(s, 0.f);
    __syncthreads();
    if (t < 3) {
        float sl = b3[t];
        for (int j = 0; j < 128; ++j) sl += h2[j] * w3[t * 128 + j];
        aw[t] = sl;
    }
    __syncthreads();
    if (t == 0) {
        float mx = fmaxf(aw[0], fmaxf(aw[1], aw[2]));
        float e0 = expf(aw[0] - mx), e1 = expf(aw[1] - mx), e2 = expf(aw[2] - mx);
        float inv = 1.f / (e0 + e1 + e2);
        aw[0] = e0 * inv; aw[1] = e1 * inv; aw[2] = e2 * inv;
    }
    __syncthreads();
    xctx[t] = aw[0] * xin[t] + aw[1] * xin[128 + t] + aw[2] * xin[256 + t];
    __syncthreads();
    float sg = f1b[t], sb = f2b[t];
    for (int j = 0; j < 128; ++j) {
        float xj = xctx[j];
        sg += xj * f1w[t * 128 + j];
        sb += xj * f2w[t * 128 + j];
    }
    out[t]       = tanhf(sg);
    out[128 + t] = tanhf(sb);
}

extern "C" void kernel_launch(void* const* d_in, const int* in_sizes, int n_in,
                              void* d_out, int out_size, void* d_ws, size_t ws_size,
                              hipStream_t stream) {
    (void)in_sizes; (void)n_in; (void)out_size; (void)ws_size;

    const float* x[3]  = {(const float*)d_in[0], (const float*)d_in[1], (const float*)d_in[2]};
    const int*   ei[3] = {(const int*)d_in[3], (const int*)d_in[4], (const int*)d_in[5]};
    const float* cw[3] = {(const float*)d_in[6], (const float*)d_in[8], (const float*)d_in[10]};
    const float* cb[3] = {(const float*)d_in[7], (const float*)d_in[9], (const float*)d_in[11]};

    // layout (binned overlaid by hpb: binned dead after k_sort3)
    char* ws = (char*)d_ws;
    int*            adj    = (int*)ws;                         //  9,600,000
    int*            deg    = (int*)(ws + 9600000);             //    600,000
    int*            rowptr = (int*)(ws + 10200000);            //    600,192
    int*            bHist  = (int*)(ws + 10800192);            //      9,408
    int*            bOff   = (int*)(ws + 10809600);            //      9,408
    int*            bCur   = (int*)(ws + 10819008);            //      9,408
    float*          g      = (float*)(ws + 10828416);          //      1,536
    unsigned short* wtg    = (unsigned short*)(ws + 10830080); //     98,304
    char*           uni    = ws + 10928384;                    // union region
    unsigned int*   binned = (unsigned int*)uni;               //  9,600,000
    unsigned int*   hpb    = (unsigned int*)uni;               // 38,400,000

    hipMemsetAsync(bHist, 0, 3 * BSTRIDE * sizeof(int), stream);
    hipMemsetAsync(g, 0, 3 * DD * sizeof(float), stream);

    dim3 bin_grid(BIN_BLOCKS, 3);
    k_wt3   <<<3, 256, 0, stream>>>(cw[0], cw[1], cw[2], wtg);
    k_bcnt3 <<<bin_grid, 256, 0, stream>>>(ei[0], ei[1], ei[2], bHist);
    k_bscan3<<<3, 64, 0, stream>>>(bHist, bOff, bCur);
    k_bin3  <<<bin_grid, 256, 0, stream>>>(ei[0], ei[1], ei[2], bCur, binned);
    k_sort3 <<<dim3(NB, 3), 256, 0, stream>>>(binned, bOff, adj, deg, rowptr);

    k_gemmb<<<dim3(NB, 3), 256, 0, stream>>>(x[0], x[1], x[2], wtg,
                                             deg, (unsigned short*)hpb, NN);
    k_gather3<<<dim3(2048, 3), 256, 0, stream>>>(hpb, rowptr, adj, deg,
                                                 cb[0], cb[1], cb[2], g, NN);

    k_head<<<1, 128, 0, stream>>>(g,
        (const float*)d_in[12], (const float*)d_in[13],
        (const float*)d_in[14], (const float*)d_in[15],
        (const float*)d_in[16], (const float*)d_in[17],
        (const float*)d_in[18], (const float*)d_in[19],
        (const float*)d_in[20], (const float*)d_in[21],
        (float*)d_out);
}

// Round 10
// 382.748 us; speedup vs baseline: 6.2474x; 1.0769x over previous
//
#include <hip/hip_runtime.h>

#define NN 50000
#define NE 800000
#define DD 128
#define NB 782          // buckets of 64 nodes
#define BSTRIDE 784
#define RPS 50016       // rowptr per-conv stride
#define CHUNK 4096
#define BIN_BLOCKS ((NE + CHUNK - 1) / CHUNK)   // 196
#define H8SCALE 64.f
#define H8INV (1.f / 64.f)

typedef float floatx4 __attribute__((ext_vector_type(4)));
typedef float floatx2 __attribute__((ext_vector_type(2)));
typedef __bf16 bf16x8 __attribute__((ext_vector_type(8)));

__device__ __forceinline__ int clampn(int v) {
    return v < 0 ? 0 : (v >= NN ? NN - 1 : v);
}
__device__ __forceinline__ unsigned int f2bf(float f) {
    union { float f; unsigned int i; } v; v.f = f;
    unsigned int lsb = (v.i >> 16) & 1u;
    v.i += 0x7fffu + lsb;
    return (v.i >> 16) & 0xFFFFu;
}

// ---- W^T bf16 precompute + zero bHist/g (folds the memsets) ----
__global__ __launch_bounds__(256) void k_wt3(const float* __restrict__ w0,
                                             const float* __restrict__ w1,
                                             const float* __restrict__ w2,
                                             unsigned short* __restrict__ wtg,
                                             int* __restrict__ bHist,
                                             float* __restrict__ g) {
    int conv = blockIdx.x;
    const float* W = conv == 0 ? w0 : conv == 1 ? w1 : w2;
    unsigned short* o = wtg + conv * DD * DD;
    for (int i = threadIdx.x; i < BSTRIDE; i += 256) bHist[conv * BSTRIDE + i] = 0;
    for (int i = threadIdx.x; i < DD; i += 256) g[conv * DD + i] = 0.f;
    for (int idx = threadIdx.x; idx < DD * DD; idx += 256) {
        int k = idx >> 7, c = idx & 127;
        o[c * DD + k] = (unsigned short)f2bf(W[idx]);
    }
}

// ---- pass 1: per-bucket edge counts ----
__global__ __launch_bounds__(256) void k_bcnt3(const int* __restrict__ e0,
                                               const int* __restrict__ e1,
                                               const int* __restrict__ e2,
                                               int* __restrict__ bHist) {
    __shared__ int hist[NB];
    const int* ei = (blockIdx.y == 0 ? e0 : blockIdx.y == 1 ? e1 : e2);
    int t = threadIdx.x;
    for (int b = t; b < NB; b += 256) hist[b] = 0;
    __syncthreads();
    int base = blockIdx.x * CHUNK;
    int chunk = NE - base; if (chunk > CHUNK) chunk = CHUNK;
    for (int i = t; i < chunk; i += 256) {
        int d = clampn(ei[NE + base + i]);
        atomicAdd(&hist[d >> 6], 1);
    }
    __syncthreads();
    for (int b = t; b < NB; b += 256)
        if (hist[b]) atomicAdd(&bHist[blockIdx.y * BSTRIDE + b], hist[b]);
}

// ---- pass 2: scan bucket counts -> bOff, bCur ----
__global__ __launch_bounds__(64) void k_bscan3(const int* __restrict__ bHist,
                                               int* __restrict__ bOff,
                                               int* __restrict__ bCur) {
    int conv = blockIdx.x;
    int lane = threadIdx.x;
    const int PER = (NB + 63) / 64;   // 13
    int basei = lane * PER;
    int loc[PER];
    int s = 0;
    for (int j = 0; j < PER; ++j) {
        int b = basei + j;
        int h = (b < NB) ? bHist[conv * BSTRIDE + b] : 0;
        loc[j] = h; s += h;
    }
    int incl = s;
    for (int off = 1; off < 64; off <<= 1) {
        int u = __shfl_up(incl, off);
        if (lane >= off) incl += u;
    }
    int run = incl - s;
    for (int j = 0; j < PER; ++j) {
        int b = basei + j;
        if (b < NB) {
            bOff[conv * BSTRIDE + b] = run;
            bCur[conv * BSTRIDE + b] = run;
            run += loc[j];
        }
    }
    if (lane == 63) bOff[conv * BSTRIDE + NB] = incl;
}

// ---- pass 3: block-local counting sort by bucket, coalesced flush ----
__global__ __launch_bounds__(256) void k_bin3(const int* __restrict__ e0,
                                              const int* __restrict__ e1,
                                              const int* __restrict__ e2,
                                              int* __restrict__ bCur,
                                              unsigned int* __restrict__ binned) {
    __shared__ int hist[NB];
    __shared__ int off[NB];
    __shared__ int delta[NB];
    __shared__ unsigned int stage[CHUNK];
    __shared__ unsigned short sbuck[CHUNK];
    const int* ei = (blockIdx.y == 0 ? e0 : blockIdx.y == 1 ? e1 : e2);
    int conv = blockIdx.y;
    int t = threadIdx.x;
    int base = blockIdx.x * CHUNK;
    int chunk = NE - base; if (chunk > CHUNK) chunk = CHUNK;

    for (int b = t; b < NB; b += 256) hist[b] = 0;
    __syncthreads();
    for (int i = t; i < chunk; i += 256) {
        int d = clampn(ei[NE + base + i]);
        atomicAdd(&hist[d >> 6], 1);
    }
    __syncthreads();
    if (t < 64) {
        const int PER = (NB + 63) / 64;
        int basei = t * PER;
        int loc[(NB + 63) / 64];
        int s = 0;
        for (int j = 0; j < PER; ++j) {
            int b = basei + j;
            int h = (b < NB) ? hist[b] : 0;
            loc[j] = h; s += h;
        }
        int incl = s;
        for (int o = 1; o < 64; o <<= 1) {
            int u = __shfl_up(incl, o);
            if (t >= o) incl += u;
        }
        int run = incl - s;
        for (int j = 0; j < PER; ++j) {
            int b = basei + j;
            if (b < NB) { off[b] = run; run += loc[j]; }
        }
    }
    __syncthreads();
    for (int b = t; b < NB; b += 256) {
        if (hist[b]) {
            int gp = atomicAdd(&bCur[conv * BSTRIDE + b], hist[b]);
            delta[b] = gp - off[b];
        }
    }
    __syncthreads();
    for (int i = t; i < chunk; i += 256) {
        int s = clampn(ei[base + i]);
        int d = clampn(ei[NE + base + i]);
        int b = d >> 6;
        int slot = atomicAdd(&off[b], 1);
        stage[slot] = (unsigned int)s | ((unsigned int)(d & 63) << 16);
        sbuck[slot] = (unsigned short)b;
    }
    __syncthreads();
    for (int i = t; i < chunk; i += 256)
        binned[(long)conv * NE + delta[sbuck[i]] + i] = stage[i];
}

// ---- pass 4: within-bucket sort by node -> adj, deg, rowptr ----
__global__ __launch_bounds__(256) void k_sort3(const unsigned int* __restrict__ binned,
                                               const int* __restrict__ bOff,
                                               int* __restrict__ adj,
                                               int* __restrict__ deg,
                                               int* __restrict__ rowptr) {
    __shared__ int cnt[64];
    __shared__ int cur[64];
    int b = blockIdx.x, conv = blockIdx.y;
    int t = threadIdx.x;
    int beg = bOff[conv * BSTRIDE + b], end = bOff[conv * BSTRIDE + b + 1];
    const unsigned int* bp = binned + (long)conv * NE;
    if (t < 64) cnt[t] = 0;
    __syncthreads();
    for (int i = beg + t; i < end; i += 256)
        atomicAdd(&cnt[(bp[i] >> 16) & 63], 1);
    __syncthreads();
    if (t < 64) {
        int c = cnt[t];
        int incl = c;
        for (int o = 1; o < 64; o <<= 1) {
            int u = __shfl_up(incl, o);
            if (t >= o) incl += u;
        }
        cur[t] = beg + incl - c;
        int v = b * 64 + t;
        if (v < NN) {
            deg[conv * NN + v] = c;
            rowptr[conv * RPS + v] = beg + incl - c;
            if (v == NN - 1) rowptr[conv * RPS + NN] = beg + incl;
        }
    }
    __syncthreads();
    for (int i = beg + t; i < end; i += 256) {
        unsigned int e = bp[i];
        int dl = (e >> 16) & 63;
        int pos = atomicAdd(&cur[dl], 1);
        adj[(long)conv * NE + pos] = (int)(e & 0xFFFFu);
    }
}

// ---- batched MFMA gemm: h' = bf16(x)@bf16(W) * rsqrt(deg+1) * 64 -> fp8 ----
__global__ __launch_bounds__(256) void k_gemmb(
    const float* __restrict__ x0, const float* __restrict__ x1, const float* __restrict__ x2,
    const unsigned short* __restrict__ wtg,
    const int* __restrict__ deg, unsigned char* __restrict__ hp8s, int n) {
    int conv = blockIdx.y;
    const float* x = conv == 0 ? x0 : conv == 1 ? x1 : x2;
    const int* dg = deg + conv * NN;
    unsigned char* hp = hp8s + (size_t)conv * NN * DD;

    __shared__ __align__(16) unsigned short wt[128 * 136];  // W^T bf16, padded
    __shared__ __align__(16) unsigned short xb[64 * 136];   // x rows bf16, padded
    int tid = threadIdx.x;
    int base = blockIdx.x * 64;

    const uint4* wg = reinterpret_cast<const uint4*>(wtg + conv * DD * DD);
#pragma unroll
    for (int it = 0; it < 8; ++it) {
        int chunk = it * 256 + tid;
        int c = chunk >> 4, gq = chunk & 15;
        *reinterpret_cast<uint4*>(&wt[c * 136 + gq * 8]) = wg[chunk];
    }
    const float4* x4p = reinterpret_cast<const float4*>(x);
#pragma unroll
    for (int it = 0; it < 8; ++it) {
        int idx = it * 256 + tid;
        int row = idx >> 5, c4 = idx & 31;
        int r = base + row;
        float4 v = (r < n) ? x4p[(long)r * 32 + c4] : float4{0.f, 0.f, 0.f, 0.f};
        unsigned int p0 = f2bf(v.x) | (f2bf(v.y) << 16);
        unsigned int p1 = f2bf(v.z) | (f2bf(v.w) << 16);
        uint2 pv = {p0, p1};
        *reinterpret_cast<uint2*>(&xb[row * 136 + c4 * 4]) = pv;
    }
    __syncthreads();

    int wave = tid >> 6, lane = tid & 63;
    int quad = lane >> 4, m = lane & 15;
    int rowb = wave * 16;

    bf16x8 a[4];
#pragma unroll
    for (int s = 0; s < 4; ++s)
        a[s] = *reinterpret_cast<const bf16x8*>(&xb[(rowb + m) * 136 + s * 32 + quad * 8]);

    floatx4 acc[8] = {};
#pragma unroll
    for (int j = 0; j < 8; ++j) {
#pragma unroll
        for (int s = 0; s < 4; ++s) {
            bf16x8 b = *reinterpret_cast<const bf16x8*>(&wt[(j * 16 + m) * 136 + s * 32 + quad * 8]);
            acc[j] = __builtin_amdgcn_mfma_f32_16x16x32_bf16(a[s], b, acc[j], 0, 0, 0);
        }
    }
#pragma unroll
    for (int r = 0; r < 4; ++r) {
        int rr = base + rowb + quad * 4 + r;
        if (rr < n) {
            float dv = rsqrtf((float)(dg[rr] + 1)) * H8SCALE;
            unsigned char* rowp = hp + (long)rr * DD;
#pragma unroll
            for (int j = 0; j < 8; ++j) {
                float v = acc[j][r] * dv;
                int p = __builtin_amdgcn_cvt_pk_fp8_f32(v, v, 0, false);
                rowp[j * 16 + m] = (unsigned char)(p & 0xFF);
            }
        }
    }
}

// ---- batched gather: wave/node, fp8 rows (1 line), 16 loads in flight ----
__global__ __launch_bounds__(256) void k_gather3(const unsigned char* __restrict__ hp8s,
                                                 const int* __restrict__ rowptr,
                                                 const int* __restrict__ adj,
                                                 const int* __restrict__ deg,
                                                 const float* __restrict__ cb0,
                                                 const float* __restrict__ cb1,
                                                 const float* __restrict__ cb2,
                                                 float* __restrict__ gout, int n) {
    int conv = blockIdx.y;
    const unsigned short* hp = reinterpret_cast<const unsigned short*>(hp8s + (size_t)conv * NN * DD);
    const int* rp = rowptr + conv * RPS;
    const int* ad = adj + (long)conv * NE;
    const int* dg = deg + conv * NN;
    const float* bias = conv == 0 ? cb0 : conv == 1 ? cb1 : cb2;
    float* go = gout + conv * DD;

    int lane = threadIdx.x & 63;
    int wv = threadIdx.x >> 6;
    int gw = blockIdx.x * 4 + wv;
    int stride = gridDim.x * 4;
    float2 b2 = reinterpret_cast<const float2*>(bias)[lane];
    float px = 0.f, py = 0.f;

    for (int v = gw; v < n; v += stride) {
        int beg = rp[v], end = rp[v + 1];
        floatx2 sf = __builtin_amdgcn_cvt_pk_f32_fp8((int)hp[(long)v * 64 + lane], false);
        float ax = sf.x, ay = sf.y;
        float cx = 0.f, cy = 0.f;
        for (int j = beg; j < end; j += 64) {
            int cnt = end - j; if (cnt > 64) cnt = 64;
            int ai = j + lane; if (ai > end - 1) ai = end - 1;
            int ent = ad[ai];
            int k = 0;
            for (; k + 16 <= cnt; k += 16) {
                int u[16];
#pragma unroll
                for (int q = 0; q < 16; ++q) {
                    int s = __builtin_amdgcn_readlane(ent, k + q);
                    u[q] = (int)hp[(long)s * 64 + lane];
                }
#pragma unroll
                for (int q = 0; q < 16; q += 2) {
                    floatx2 f0 = __builtin_amdgcn_cvt_pk_f32_fp8(u[q], false);
                    floatx2 f1 = __builtin_amdgcn_cvt_pk_f32_fp8(u[q + 1], false);
                    ax += f0.x; ay += f0.y;
                    cx += f1.x; cy += f1.y;
                }
            }
            if (k < cnt) {
                int u[16];
#pragma unroll
                for (int q = 0; q < 16; ++q) {
                    int idx = k + q; if (idx > cnt - 1) idx = cnt - 1;
                    int s = __builtin_amdgcn_readlane(ent, idx);
                    u[q] = (int)hp[(long)s * 64 + lane];
                }
#pragma unroll
                for (int q = 0; q < 16; ++q)
                    if (k + q >= cnt) u[q] = 0;
#pragma unroll
                for (int q = 0; q < 16; q += 2) {
                    floatx2 f0 = __builtin_amdgcn_cvt_pk_f32_fp8(u[q], false);
                    floatx2 f1 = __builtin_amdgcn_cvt_pk_f32_fp8(u[q + 1], false);
                    ax += f0.x; ay += f0.y;
                    cx += f1.x; cy += f1.y;
                }
            }
        }
        ax += cx; ay += cy;
        float dv = rsqrtf((float)(dg[v] + 1)) * H8INV;
        px += fmaxf(dv * ax + b2.x, 0.f);
        py += fmaxf(dv * ay + b2.y, 0.f);
    }
    __shared__ float red[4][DD];
    red[wv][lane * 2] = px;
    red[wv][lane * 2 + 1] = py;
    __syncthreads();
    int t = threadIdx.x;
    if (t < DD)
        unsafeAtomicAdd(&go[t], red[0][t] + red[1][t] + red[2][t] + red[3][t]);
}

// ---- head MLP: 256 threads, float4 weight reads, split-j reduction ----
__global__ __launch_bounds__(256) void k_head(const float* __restrict__ g,
    const float* __restrict__ w1, const float* __restrict__ b1,
    const float* __restrict__ w2, const float* __restrict__ b2,
    const float* __restrict__ w3, const float* __restrict__ b3,
    const float* __restrict__ f1w, const float* __restrict__ f1b,
    const float* __restrict__ f2w, const float* __restrict__ f2b,
    float* __restrict__ out) {
    __shared__ float xin[384], part[256], h1[128], h2[128], aw[3], xctx[128];
    int t = threadIdx.x;
    int o = t & 127, half = t >> 7;
    for (int i = t; i < 384; i += 256) xin[i] = g[i];
    __syncthreads();
    // fc1: out o, thread-half splits j in [0,192)/[192,384)
    {
        const float4* wrow = reinterpret_cast<const float4*>(w1 + o * 384 + half * 192);
        const float* xi = xin + half * 192;
        float s = 0.f;
#pragma unroll
        for (int j4 = 0; j4 < 48; ++j4) {
            float4 w = wrow[j4];
            s += w.x * xi[j4 * 4] + w.y * xi[j4 * 4 + 1] + w.z * xi[j4 * 4 + 2] + w.w * xi[j4 * 4 + 3];
        }
        part[t] = s;
    }
    __syncthreads();
    if (t < 128) h1[t] = fmaxf(part[t] + part[t + 128] + b1[t], 0.f);
    __syncthreads();
    // fc2
    {
        const float4* wrow = reinterpret_cast<const float4*>(w2 + o * 128 + half * 64);
        const float* xi = h1 + half * 64;
        float s = 0.f;
#pragma unroll
        for (int j4 = 0; j4 < 16; ++j4) {
            float4 w = wrow[j4];
            s += w.x * xi[j4 * 4] + w.y * xi[j4 * 4 + 1] + w.z * xi[j4 * 4 + 2] + w.w * xi[j4 * 4 + 3];
        }
        part[t] = s;
    }
    __syncthreads();
    if (t < 128) h2[t] = fmaxf(part[t] + part[t + 128] + b2[t], 0.f);
    __syncthreads();
    if (t < 3) {
        float sl = b3[t];
        for (int j = 0; j < 128; ++j) sl += h2[j] * w3[t * 128 + j];
        aw[t] = sl;
    }
    __syncthreads();
    if (t == 0) {
        float mx = fmaxf(aw[0], fmaxf(aw[1], aw[2]));
        float e0 = expf(aw[0] - mx), e1 = expf(aw[1] - mx), e2 = expf(aw[2] - mx);
        float inv = 1.f / (e0 + e1 + e2);
        aw[0] = e0 * inv; aw[1] = e1 * inv; aw[2] = e2 * inv;
    }
    __syncthreads();
    if (t < 128) xctx[t] = aw[0] * xin[t] + aw[1] * xin[128 + t] + aw[2] * xin[256 + t];
    __syncthreads();
    // FiLM: half 0 -> gamma (f1), half 1 -> beta (f2), in parallel
    {
        const float* fw = half ? f2w : f1w;
        const float* fb = half ? f2b : f1b;
        const float4* wrow = reinterpret_cast<const float4*>(fw + o * 128);
        float s = fb[o];
#pragma unroll
        for (int j4 = 0; j4 < 32; ++j4) {
            float4 w = wrow[j4];
            s += w.x * xctx[j4 * 4] + w.y * xctx[j4 * 4 + 1] + w.z * xctx[j4 * 4 + 2] + w.w * xctx[j4 * 4 + 3];
        }
        out[half * 128 + o] = tanhf(s);
    }
}

extern "C" void kernel_launch(void* const* d_in, const int* in_sizes, int n_in,
                              void* d_out, int out_size, void* d_ws, size_t ws_size,
                              hipStream_t stream) {
    (void)in_sizes; (void)n_in; (void)out_size; (void)ws_size;

    const float* x[3]  = {(const float*)d_in[0], (const float*)d_in[1], (const float*)d_in[2]};
    const int*   ei[3] = {(const int*)d_in[3], (const int*)d_in[4], (const int*)d_in[5]};
    const float* cw[3] = {(const float*)d_in[6], (const float*)d_in[8], (const float*)d_in[10]};
    const float* cb[3] = {(const float*)d_in[7], (const float*)d_in[9], (const float*)d_in[11]};

    // layout (binned overlaid by hp8: binned dead after k_sort3)
    char* ws = (char*)d_ws;
    int*            adj    = (int*)ws;                         //  9,600,000
    int*            deg    = (int*)(ws + 9600000);             //    600,000
    int*            rowptr = (int*)(ws + 10200000);            //    600,192
    int*            bHist  = (int*)(ws + 10800192);            //      9,408
    int*            bOff   = (int*)(ws + 10809600);            //      9,408
    int*            bCur   = (int*)(ws + 10819008);            //      9,408
    float*          g      = (float*)(ws + 10828416);          //      1,536
    unsigned short* wtg    = (unsigned short*)(ws + 10830080); //     98,304
    char*           uni    = ws + 10928384;                    // union region
    unsigned int*   binned = (unsigned int*)uni;               //  9,600,000
    unsigned char*  hp8    = (unsigned char*)uni;              // 19,200,000

    dim3 bin_grid(BIN_BLOCKS, 3);
    k_wt3   <<<3, 256, 0, stream>>>(cw[0], cw[1], cw[2], wtg, bHist, g);
    k_bcnt3 <<<bin_grid, 256, 0, stream>>>(ei[0], ei[1], ei[2], bHist);
    k_bscan3<<<3, 64, 0, stream>>>(bHist, bOff, bCur);
    k_bin3  <<<bin_grid, 256, 0, stream>>>(ei[0], ei[1], ei[2], bCur, binned);
    k_sort3 <<<dim3(NB, 3), 256, 0, stream>>>(binned, bOff, adj, deg, rowptr);

    k_gemmb<<<dim3(NB, 3), 256, 0, stream>>>(x[0], x[1], x[2], wtg, deg, hp8, NN);
    k_gather3<<<dim3(2048, 3), 256, 0, stream>>>(hp8, rowptr, adj, deg,
                                                 cb[0], cb[1], cb[2], g, NN);

    k_head<<<1, 256, 0, stream>>>(g,
        (const float*)d_in[12], (const float*)d_in[13],
        (const float*)d_in[14], (const float*)d_in[15],
        (const float*)d_in[16], (const float*)d_in[17],
        (const float*)d_in[18], (const float*)d_in[19],
        (const float*)d_in[20], (const float*)d_in[21],
        (float*)d_out);
}